// Round 1
// baseline (351.219 us; speedup 1.0000x reference)
//
#include <hip/hip_runtime.h>
#include <hip/hip_bf16.h>
#include <stdint.h>

// Problem constants (match reference)
#define Bq   2
#define Tq   4096
#define DIMq 1024
#define HIDq 512
#define Eq   16
#define Mq   (Bq * Tq)   // 8192 flattened token rows

typedef __attribute__((ext_vector_type(8))) short bf16x8;   // 8 bf16 = 4 VGPRs (guide §3)
typedef __attribute__((ext_vector_type(4))) float f32x4;

// --- bf16 helpers (RNE, matches XLA rounding) ---
__device__ __forceinline__ unsigned int f2bf(float f) {
  unsigned int u = __builtin_bit_cast(unsigned int, f);
  return (u + 0x7FFFu + ((u >> 16) & 1u)) >> 16;
}
__device__ __forceinline__ float bf2f(unsigned int s) {
  unsigned int u = s << 16;
  return __builtin_bit_cast(float, u);
}
__device__ __forceinline__ unsigned long long pack4(const float4 v) {
  return (unsigned long long)f2bf(v.x)
       | ((unsigned long long)f2bf(v.y) << 16)
       | ((unsigned long long)f2bf(v.z) << 32)
       | ((unsigned long long)f2bf(v.w) << 48);
}

// ---------------------------------------------------------------------------
// Kernel 0: per-batch-row exclusive-cumsum of expert token counts.
// seg_off[b][e] .. seg_off[b][e+1] is expert e's contiguous token slice.
// ---------------------------------------------------------------------------
__global__ void setup_kernel(const int* __restrict__ counts, int* __restrict__ seg_off) {
  int b = blockIdx.x;
  if (threadIdx.x == 0) {
    int s = 0;
    seg_off[b * (Eq + 1)] = 0;
    for (int e = 0; e < Eq; ++e) {
      s += counts[b * Eq + e];
      seg_off[b * (Eq + 1) + e + 1] = s;
    }
  }
}

// ---------------------------------------------------------------------------
// Kernel 1: h[m, n] = bf16( silu(x.w1^T) * (x.w3^T) )   m over B*T, n over HID
// 64x64 output tile, BK=64, 4 waves (each 32x32 = 2x2 of 16x16x32 MFMA).
// Per m-tile, loop over expert segments intersecting it; compute full tile
// with that expert's weights, write only rows inside the segment.
// ---------------------------------------------------------------------------
__global__ __launch_bounds__(256) void gemm1_kernel(
    const float* __restrict__ x, const float* __restrict__ w1,
    const float* __restrict__ w3, const int* __restrict__ seg_off,
    unsigned short* __restrict__ hbuf) {
  const int mt = blockIdx.x;            // 0..127
  const int nt = blockIdx.y;            // 0..7
  const int t0 = mt * 64;               // flat row base (b*T + t)
  const int n0 = nt * 64;
  const int b  = t0 / Tq;
  const int tl0 = t0 - b * Tq;          // local token index of tile start

  __shared__ unsigned short xs[2][64 * 64];
  __shared__ unsigned short w1s[2][64 * 64];
  __shared__ unsigned short w3s[2][64 * 64];

  const int tid  = threadIdx.x;
  const int lane = tid & 63;
  const int wv   = tid >> 6;            // wave 0..3
  const int wm   = (wv >> 1) << 5;      // 0 / 32
  const int wn   = (wv & 1) << 5;       // 0 / 32
  const int q    = lane >> 4;           // quarter-wave
  const int l15  = lane & 15;

  // staging coords: 16 rows x 16 float4-cols per pass, 4 passes
  const int srow = tid >> 4;            // 0..15
  const int scol = (tid & 15) << 2;     // fp32 element col
  const int sbyte_col = (scol << 1);    // byte col in bf16 LDS row (8B granule)

  #pragma unroll 1
  for (int e = 0; e < Eq; ++e) {
    const int lo = seg_off[b * (Eq + 1) + e];
    const int hi = seg_off[b * (Eq + 1) + e + 1];
    const int s  = lo > tl0 ? lo : tl0;
    const int en = hi < tl0 + 64 ? hi : tl0 + 64;
    if (s >= en) continue;

    const float* __restrict__ w1e = w1 + (size_t)e * HIDq * DIMq;
    const float* __restrict__ w3e = w3 + (size_t)e * HIDq * DIMq;

    f32x4 acc1[2][2], acc3[2][2];
    #pragma unroll
    for (int i = 0; i < 2; ++i)
      #pragma unroll
      for (int j = 0; j < 2; ++j) { acc1[i][j] = (f32x4)0.f; acc3[i][j] = (f32x4)0.f; }

    float4 rx[4], r1[4], r3[4];

    auto stage_load = [&](int k0) {
      #pragma unroll
      for (int it = 0; it < 4; ++it) {
        const int r = srow + it * 16;
        rx[it] = *(const float4*)(x   + (size_t)(t0 + r) * DIMq + k0 + scol);
        r1[it] = *(const float4*)(w1e + (size_t)(n0 + r) * DIMq + k0 + scol);
        r3[it] = *(const float4*)(w3e + (size_t)(n0 + r) * DIMq + k0 + scol);
      }
    };
    auto stage_write = [&](int bi) {
      #pragma unroll
      for (int it = 0; it < 4; ++it) {
        const int r = srow + it * 16;
        const int byte = r * 128 + (sbyte_col ^ ((r & 7) << 4));  // XOR-swizzle (G4)
        *(unsigned long long*)((char*)&xs[bi][0]  + byte) = pack4(rx[it]);
        *(unsigned long long*)((char*)&w1s[bi][0] + byte) = pack4(r1[it]);
        *(unsigned long long*)((char*)&w3s[bi][0] + byte) = pack4(r3[it]);
      }
    };
    auto compute = [&](int bi) {
      const char* xb  = (const char*)&xs[bi][0];
      const char* b1p = (const char*)&w1s[bi][0];
      const char* b3p = (const char*)&w3s[bi][0];
      #pragma unroll
      for (int ks = 0; ks < 64; ks += 32) {
        const int kb  = (ks + (q << 3)) << 1;        // byte col of this lane's 8 bf16
        const int swz = kb ^ ((l15 & 7) << 4);
        const int ra  = (wm + l15) * 128 + swz;
        const int rb  = (wn + l15) * 128 + swz;
        bf16x8 a0 = *(const bf16x8*)(xb + ra);
        bf16x8 a1 = *(const bf16x8*)(xb + ra + 2048);
        bf16x8 u0 = *(const bf16x8*)(b1p + rb);
        bf16x8 u1 = *(const bf16x8*)(b1p + rb + 2048);
        bf16x8 v0 = *(const bf16x8*)(b3p + rb);
        bf16x8 v1 = *(const bf16x8*)(b3p + rb + 2048);
        acc1[0][0] = __builtin_amdgcn_mfma_f32_16x16x32_bf16(a0, u0, acc1[0][0], 0, 0, 0);
        acc1[0][1] = __builtin_amdgcn_mfma_f32_16x16x32_bf16(a0, u1, acc1[0][1], 0, 0, 0);
        acc1[1][0] = __builtin_amdgcn_mfma_f32_16x16x32_bf16(a1, u0, acc1[1][0], 0, 0, 0);
        acc1[1][1] = __builtin_amdgcn_mfma_f32_16x16x32_bf16(a1, u1, acc1[1][1], 0, 0, 0);
        acc3[0][0] = __builtin_amdgcn_mfma_f32_16x16x32_bf16(a0, v0, acc3[0][0], 0, 0, 0);
        acc3[0][1] = __builtin_amdgcn_mfma_f32_16x16x32_bf16(a0, v1, acc3[0][1], 0, 0, 0);
        acc3[1][0] = __builtin_amdgcn_mfma_f32_16x16x32_bf16(a1, v0, acc3[1][0], 0, 0, 0);
        acc3[1][1] = __builtin_amdgcn_mfma_f32_16x16x32_bf16(a1, v1, acc3[1][1], 0, 0, 0);
      }
    };

    stage_load(0);
    stage_write(0);
    __syncthreads();
    int cur = 0;
    #pragma unroll 1
    for (int k0 = 0; k0 < DIMq; k0 += 64) {
      const bool more = (k0 + 64) < DIMq;
      if (more) stage_load(k0 + 64);     // issue early: hides under MFMA (T14-lite)
      compute(cur);
      if (more) stage_write(cur ^ 1);    // write late, other buffer
      __syncthreads();                   // one barrier per K-step
      cur ^= 1;
    }

    // epilogue: SwiGLU with reference-matching bf16 roundings, masked rows
    const int rlo = s - tl0, rhi = en - tl0;
    #pragma unroll
    for (int i = 0; i < 2; ++i)
      #pragma unroll
      for (int j = 0; j < 2; ++j)
        #pragma unroll
        for (int rr = 0; rr < 4; ++rr) {
          const int row = wm + i * 16 + q * 4 + rr;
          if (row >= rlo && row < rhi) {
            const float a  = bf2f(f2bf(acc1[i][j][rr]));       // bf16 gemm output
            const float c  = bf2f(f2bf(acc3[i][j][rr]));
            const float sg = bf2f(f2bf(1.f / (1.f + __expf(-a))));
            const float tt = bf2f(f2bf(a * sg));               // silu in bf16 steps
            hbuf[(size_t)(t0 + row) * HIDq + n0 + wn + j * 16 + l15] =
                (unsigned short)f2bf(tt * c);
          }
        }
  }
}

// ---------------------------------------------------------------------------
// Kernel 2: out[m, n] = float(bf16( h . w2^T ))   n over DIM, K = HID
// ---------------------------------------------------------------------------
__global__ __launch_bounds__(256) void gemm2_kernel(
    const unsigned short* __restrict__ hbuf, const float* __restrict__ w2,
    const int* __restrict__ seg_off, float* __restrict__ out) {
  const int mt = blockIdx.x;            // 0..127
  const int nt = blockIdx.y;            // 0..15
  const int t0 = mt * 64;
  const int n0 = nt * 64;
  const int b  = t0 / Tq;
  const int tl0 = t0 - b * Tq;

  __shared__ unsigned short hs[2][64 * 64];
  __shared__ unsigned short w2s[2][64 * 64];

  const int tid  = threadIdx.x;
  const int lane = tid & 63;
  const int wv   = tid >> 6;
  const int wm   = (wv >> 1) << 5;
  const int wn   = (wv & 1) << 5;
  const int q    = lane >> 4;
  const int l15  = lane & 15;

  const int srow = tid >> 4;            // fp32 w2 staging: 16 rows x 16 float4
  const int scol = (tid & 15) << 2;
  const int sbyte_col = (scol << 1);
  const int hrow = tid >> 3;            // bf16 h staging: 32 rows x 8 uint4
  const int hcol = (tid & 7) << 3;      // elem col
  const int hbyte_col = (hcol << 1);    // 16B granule aligned

  #pragma unroll 1
  for (int e = 0; e < Eq; ++e) {
    const int lo = seg_off[b * (Eq + 1) + e];
    const int hi = seg_off[b * (Eq + 1) + e + 1];
    const int s  = lo > tl0 ? lo : tl0;
    const int en = hi < tl0 + 64 ? hi : tl0 + 64;
    if (s >= en) continue;

    const float* __restrict__ w2e = w2 + (size_t)e * DIMq * HIDq;

    f32x4 acc[2][2];
    #pragma unroll
    for (int i = 0; i < 2; ++i)
      #pragma unroll
      for (int j = 0; j < 2; ++j) acc[i][j] = (f32x4)0.f;

    uint4  rh[2];
    float4 r2[4];

    auto stage_load = [&](int k0) {
      #pragma unroll
      for (int it = 0; it < 2; ++it)
        rh[it] = *(const uint4*)(hbuf + (size_t)(t0 + hrow + it * 32) * HIDq + k0 + hcol);
      #pragma unroll
      for (int it = 0; it < 4; ++it)
        r2[it] = *(const float4*)(w2e + (size_t)(n0 + srow + it * 16) * HIDq + k0 + scol);
    };
    auto stage_write = [&](int bi) {
      #pragma unroll
      for (int it = 0; it < 2; ++it) {
        const int r = hrow + it * 32;
        const int byte = r * 128 + (hbyte_col ^ ((r & 7) << 4));
        *(uint4*)((char*)&hs[bi][0] + byte) = rh[it];
      }
      #pragma unroll
      for (int it = 0; it < 4; ++it) {
        const int r = srow + it * 16;
        const int byte = r * 128 + (sbyte_col ^ ((r & 7) << 4));
        *(unsigned long long*)((char*)&w2s[bi][0] + byte) = pack4(r2[it]);
      }
    };
    auto compute = [&](int bi) {
      const char* hp = (const char*)&hs[bi][0];
      const char* wp = (const char*)&w2s[bi][0];
      #pragma unroll
      for (int ks = 0; ks < 64; ks += 32) {
        const int kb  = (ks + (q << 3)) << 1;
        const int swz = kb ^ ((l15 & 7) << 4);
        const int ra  = (wm + l15) * 128 + swz;
        const int rb  = (wn + l15) * 128 + swz;
        bf16x8 a0 = *(const bf16x8*)(hp + ra);
        bf16x8 a1 = *(const bf16x8*)(hp + ra + 2048);
        bf16x8 b0 = *(const bf16x8*)(wp + rb);
        bf16x8 b1 = *(const bf16x8*)(wp + rb + 2048);
        acc[0][0] = __builtin_amdgcn_mfma_f32_16x16x32_bf16(a0, b0, acc[0][0], 0, 0, 0);
        acc[0][1] = __builtin_amdgcn_mfma_f32_16x16x32_bf16(a0, b1, acc[0][1], 0, 0, 0);
        acc[1][0] = __builtin_amdgcn_mfma_f32_16x16x32_bf16(a1, b0, acc[1][0], 0, 0, 0);
        acc[1][1] = __builtin_amdgcn_mfma_f32_16x16x32_bf16(a1, b1, acc[1][1], 0, 0, 0);
      }
    };

    stage_load(0);
    stage_write(0);
    __syncthreads();
    int cur = 0;
    #pragma unroll 1
    for (int k0 = 0; k0 < HIDq; k0 += 64) {
      const bool more = (k0 + 64) < HIDq;
      if (more) stage_load(k0 + 64);
      compute(cur);
      if (more) stage_write(cur ^ 1);
      __syncthreads();
      cur ^= 1;
    }

    const int rlo = s - tl0, rhi = en - tl0;
    #pragma unroll
    for (int i = 0; i < 2; ++i)
      #pragma unroll
      for (int j = 0; j < 2; ++j)
        #pragma unroll
        for (int rr = 0; rr < 4; ++rr) {
          const int row = wm + i * 16 + q * 4 + rr;
          if (row >= rlo && row < rhi) {
            out[(size_t)(t0 + row) * DIMq + n0 + wn + j * 16 + l15] =
                bf2f(f2bf(acc[i][j][rr]));   // reference accumulates in bf16 then casts
          }
        }
  }
}

// ---------------------------------------------------------------------------
extern "C" void kernel_launch(void* const* d_in, const int* in_sizes, int n_in,
                              void* d_out, int out_size, void* d_ws, size_t ws_size,
                              hipStream_t stream) {
  const float* x      = (const float*)d_in[0];
  const int*   counts = (const int*)d_in[1];
  const float* w1     = (const float*)d_in[2];
  const float* w2     = (const float*)d_in[3];
  const float* w3     = (const float*)d_in[4];
  float* out = (float*)d_out;

  int* seg_off = (int*)d_ws;                                   // B*(E+1) ints
  unsigned short* hbuf = (unsigned short*)((char*)d_ws + 256); // 8192*512 bf16 = 8 MB

  setup_kernel<<<dim3(Bq), 64, 0, stream>>>(counts, seg_off);
  gemm1_kernel<<<dim3(Mq / 64, HIDq / 64), 256, 0, stream>>>(x, w1, w3, seg_off, hbuf);
  gemm2_kernel<<<dim3(Mq / 64, DIMq / 64), 256, 0, stream>>>(hbuf, w2, seg_off, out);
}

// Round 4
// 311.731 us; speedup vs baseline: 1.1267x; 1.1267x over previous
//
#include <hip/hip_runtime.h>
#include <hip/hip_bf16.h>
#include <stdint.h>

// Problem constants (match reference)
#define Bq   2
#define Tq   4096
#define DIMq 1024
#define HIDq 512
#define Eq   16
#define Mq   (Bq * Tq)   // 8192 flattened token rows

typedef __attribute__((ext_vector_type(8))) short bf16x8;   // 8 bf16 = 4 VGPRs
typedef __attribute__((ext_vector_type(4))) float f32x4;
typedef unsigned long long ull;

// --- bf16 helpers (RNE, matches XLA rounding) ---
__device__ __forceinline__ unsigned int f2bf(float f) {
  unsigned int u = __builtin_bit_cast(unsigned int, f);
  return (u + 0x7FFFu + ((u >> 16) & 1u)) >> 16;
}
__device__ __forceinline__ float bf2f(unsigned int s) {
  unsigned int u = s << 16;
  return __builtin_bit_cast(float, u);
}
__device__ __forceinline__ ull pack4(const float4 v) {
  return (ull)f2bf(v.x)
       | ((ull)f2bf(v.y) << 16)
       | ((ull)f2bf(v.z) << 32)
       | ((ull)f2bf(v.w) << 48);
}

// async global->LDS, 16B per lane; lds ptr must be WAVE-UNIFORM base (HW adds lane*16)
#define GLOAD16(gp, lp)                                                        \
  __builtin_amdgcn_global_load_lds(                                            \
      (const __attribute__((address_space(1))) unsigned int*)(gp),             \
      (__attribute__((address_space(3))) unsigned int*)(lp), 16, 0, 0)

// ---------------------------------------------------------------------------
// Kernel A: fp32 -> bf16 conversion for x, w1, w2, w3 (each 8,388,608 floats).
// blockIdx.y selects the array. Memory-bound: 128 MB read + 64 MB write.
// ---------------------------------------------------------------------------
__global__ __launch_bounds__(256) void convert4_kernel(
    const float* __restrict__ x,  const float* __restrict__ w1,
    const float* __restrict__ w2, const float* __restrict__ w3,
    ull* __restrict__ xb, ull* __restrict__ w1b,
    ull* __restrict__ w2b, ull* __restrict__ w3b) {
  const float* s;
  ull* d;
  switch (blockIdx.y) {
    case 0:  s = x;  d = xb;  break;
    case 1:  s = w1; d = w1b; break;
    case 2:  s = w2; d = w2b; break;
    default: s = w3; d = w3b; break;
  }
  const int N4 = (8388608 / 4);  // float4 groups per array
  for (int i = blockIdx.x * blockDim.x + threadIdx.x; i < N4;
       i += gridDim.x * blockDim.x) {
    float4 v = ((const float4*)s)[i];
    d[i] = pack4(v);
  }
}

// ---------------------------------------------------------------------------
// Kernel 0: per-batch exclusive cumsum of expert token counts.
// ---------------------------------------------------------------------------
__global__ void setup_kernel(const int* __restrict__ counts, int* __restrict__ seg_off) {
  int b = blockIdx.x;
  if (threadIdx.x == 0) {
    int s = 0;
    seg_off[b * (Eq + 1)] = 0;
    for (int e = 0; e < Eq; ++e) {
      s += counts[b * Eq + e];
      seg_off[b * (Eq + 1) + e + 1] = s;
    }
  }
}

// ---------------------------------------------------------------------------
// Kernel 1: h = bf16( silu(x.w1^T) * (x.w3^T) ), all-bf16 inputs.
// Tile: 128m x 64n, BK=64, 4 waves (2x2), wave tile 64x32.
// Staging: global_load_lds dwordx4 into linear LDS (m97 structure).
// ---------------------------------------------------------------------------
__global__ __launch_bounds__(256) void gemm1_kernel(
    const unsigned short* __restrict__ xb, const unsigned short* __restrict__ w1b,
    const unsigned short* __restrict__ w3b, const int* __restrict__ seg_off,
    unsigned short* __restrict__ hbuf) {
  const int nt  = blockIdx.x;           // 0..7  (HID/64)
  const int mt  = blockIdx.y;           // 0..63 (M/128)
  const int t0  = mt * 128;
  const int n0  = nt * 64;
  const int b   = t0 >> 12;
  const int tl0 = t0 & (Tq - 1);

  __shared__ unsigned short As[128 * 64];   // 16 KB, row-major [128][64]
  __shared__ unsigned short W1s[64 * 64];   // 8 KB
  __shared__ unsigned short W3s[64 * 64];   // 8 KB

  const int tid  = threadIdx.x;
  const int lane = tid & 63;
  const int wv   = tid >> 6;
  const int wm2  = (wv >> 1) * 64;      // wave m-offset (0/64)
  const int wn2  = (wv & 1) * 32;       // wave n-offset (0/32)
  const int q    = lane >> 4;
  const int l15  = lane & 15;

  #pragma unroll 1
  for (int e = 0; e < Eq; ++e) {
    const int lo = seg_off[b * (Eq + 1) + e];
    const int hi = seg_off[b * (Eq + 1) + e + 1];
    const int s  = lo > tl0 ? lo : tl0;
    const int en = hi < tl0 + 128 ? hi : tl0 + 128;
    if (s >= en) continue;

    const unsigned short* __restrict__ w1e = w1b + (size_t)e * HIDq * DIMq;
    const unsigned short* __restrict__ w3e = w3b + (size_t)e * HIDq * DIMq;

    f32x4 acc1[4][2], acc3[4][2];
    #pragma unroll
    for (int i = 0; i < 4; ++i)
      #pragma unroll
      for (int j = 0; j < 2; ++j) { acc1[i][j] = (f32x4)0.f; acc3[i][j] = (f32x4)0.f; }

    #pragma unroll 1
    for (int k0 = 0; k0 < DIMq; k0 += 64) {
      // ---- stage (async, no VGPR round-trip) ----
      #pragma unroll
      for (int it = 0; it < 4; ++it) {                     // A: 128x64 bf16
        const int c = it * 256 + tid;
        const int row = c >> 3, kc = (c & 7) << 3;
        GLOAD16(xb + (size_t)(t0 + row) * DIMq + k0 + kc,
                (char*)As + it * 4096 + wv * 1024);
      }
      #pragma unroll
      for (int it = 0; it < 2; ++it) {                     // W1,W3: 64x64 each
        const int c = it * 256 + tid;
        const int row = c >> 3, kc = (c & 7) << 3;
        GLOAD16(w1e + (size_t)(n0 + row) * DIMq + k0 + kc,
                (char*)W1s + it * 4096 + wv * 1024);
        GLOAD16(w3e + (size_t)(n0 + row) * DIMq + k0 + kc,
                (char*)W3s + it * 4096 + wv * 1024);
      }
      __syncthreads();   // compiler drains vmcnt before barrier

      // ---- compute ----
      #pragma unroll
      for (int ks = 0; ks < 2; ++ks) {
        const int kb = ks * 64 + q * 16;   // byte offset within 128B row
        bf16x8 a[4], u[2], v[2];
        #pragma unroll
        for (int i = 0; i < 4; ++i)
          a[i] = *(const bf16x8*)((const char*)As + (wm2 + i * 16 + l15) * 128 + kb);
        #pragma unroll
        for (int j = 0; j < 2; ++j) {
          u[j] = *(const bf16x8*)((const char*)W1s + (wn2 + j * 16 + l15) * 128 + kb);
          v[j] = *(const bf16x8*)((const char*)W3s + (wn2 + j * 16 + l15) * 128 + kb);
        }
        #pragma unroll
        for (int i = 0; i < 4; ++i)
          #pragma unroll
          for (int j = 0; j < 2; ++j) {
            acc1[i][j] = __builtin_amdgcn_mfma_f32_16x16x32_bf16(a[i], u[j], acc1[i][j], 0, 0, 0);
            acc3[i][j] = __builtin_amdgcn_mfma_f32_16x16x32_bf16(a[i], v[j], acc3[i][j], 0, 0, 0);
          }
      }
      __syncthreads();
    }

    // ---- epilogue: SwiGLU with reference-matching bf16 roundings ----
    const int rlo = s - tl0, rhi = en - tl0;
    #pragma unroll
    for (int i = 0; i < 4; ++i)
      #pragma unroll
      for (int j = 0; j < 2; ++j)
        #pragma unroll
        for (int rr = 0; rr < 4; ++rr) {
          const int row = wm2 + i * 16 + q * 4 + rr;
          if (row >= rlo && row < rhi) {
            const float aa = bf2f(f2bf(acc1[i][j][rr]));
            const float cc = bf2f(f2bf(acc3[i][j][rr]));
            const float sg = bf2f(f2bf(1.f / (1.f + __expf(-aa))));
            const float tt = bf2f(f2bf(aa * sg));
            hbuf[(size_t)(t0 + row) * HIDq + n0 + wn2 + j * 16 + l15] =
                (unsigned short)f2bf(tt * cc);
          }
        }
  }
}

// ---------------------------------------------------------------------------
// Kernel 2: out = f32( bf16( h . w2^T ) ).  Tile 128m x 128n, BK=64.
// 4 waves (2x2), wave tile 64x64, acc[4][4].
// ---------------------------------------------------------------------------
__global__ __launch_bounds__(256) void gemm2_kernel(
    const unsigned short* __restrict__ hb, const unsigned short* __restrict__ w2b,
    const int* __restrict__ seg_off, float* __restrict__ out) {
  const int nt  = blockIdx.x;           // 0..7 (DIM/128)
  const int mt  = blockIdx.y;           // 0..63
  const int t0  = mt * 128;
  const int n0  = nt * 128;
  const int b   = t0 >> 12;
  const int tl0 = t0 & (Tq - 1);

  __shared__ unsigned short Hs[128 * 64];   // 16 KB
  __shared__ unsigned short Bs[128 * 64];   // 16 KB

  const int tid  = threadIdx.x;
  const int lane = tid & 63;
  const int wv   = tid >> 6;
  const int wm2  = (wv >> 1) * 64;
  const int wn2  = (wv & 1) * 64;
  const int q    = lane >> 4;
  const int l15  = lane & 15;

  #pragma unroll 1
  for (int e = 0; e < Eq; ++e) {
    const int lo = seg_off[b * (Eq + 1) + e];
    const int hi = seg_off[b * (Eq + 1) + e + 1];
    const int s  = lo > tl0 ? lo : tl0;
    const int en = hi < tl0 + 128 ? hi : tl0 + 128;
    if (s >= en) continue;

    const unsigned short* __restrict__ w2e = w2b + (size_t)e * DIMq * HIDq;

    f32x4 acc[4][4];
    #pragma unroll
    for (int i = 0; i < 4; ++i)
      #pragma unroll
      for (int j = 0; j < 4; ++j) acc[i][j] = (f32x4)0.f;

    #pragma unroll 1
    for (int k0 = 0; k0 < HIDq; k0 += 64) {
      #pragma unroll
      for (int it = 0; it < 4; ++it) {                     // H: 128x64
        const int c = it * 256 + tid;
        const int row = c >> 3, kc = (c & 7) << 3;
        GLOAD16(hb + (size_t)(t0 + row) * HIDq + k0 + kc,
                (char*)Hs + it * 4096 + wv * 1024);
        GLOAD16(w2e + (size_t)(n0 + row) * HIDq + k0 + kc,  // W2: 128x64
                (char*)Bs + it * 4096 + wv * 1024);
      }
      __syncthreads();

      #pragma unroll
      for (int ks = 0; ks < 2; ++ks) {
        const int kb = ks * 64 + q * 16;
        bf16x8 a[4], w[4];
        #pragma unroll
        for (int i = 0; i < 4; ++i) {
          a[i] = *(const bf16x8*)((const char*)Hs + (wm2 + i * 16 + l15) * 128 + kb);
          w[i] = *(const bf16x8*)((const char*)Bs + (wn2 + i * 16 + l15) * 128 + kb);
        }
        #pragma unroll
        for (int i = 0; i < 4; ++i)
          #pragma unroll
          for (int j = 0; j < 4; ++j)
            acc[i][j] = __builtin_amdgcn_mfma_f32_16x16x32_bf16(a[i], w[j], acc[i][j], 0, 0, 0);
      }
      __syncthreads();
    }

    const int rlo = s - tl0, rhi = en - tl0;
    #pragma unroll
    for (int i = 0; i < 4; ++i)
      #pragma unroll
      for (int j = 0; j < 4; ++j)
        #pragma unroll
        for (int rr = 0; rr < 4; ++rr) {
          const int row = wm2 + i * 16 + q * 4 + rr;
          if (row >= rlo && row < rhi) {
            out[(size_t)(t0 + row) * DIMq + n0 + wn2 + j * 16 + l15] =
                bf2f(f2bf(acc[i][j][rr]));   // reference rounds y to bf16
          }
        }
  }
}

// ---------------------------------------------------------------------------
extern "C" void kernel_launch(void* const* d_in, const int* in_sizes, int n_in,
                              void* d_out, int out_size, void* d_ws, size_t ws_size,
                              hipStream_t stream) {
  const float* x      = (const float*)d_in[0];
  const int*   counts = (const int*)d_in[1];
  const float* w1     = (const float*)d_in[2];
  const float* w2     = (const float*)d_in[3];
  const float* w3     = (const float*)d_in[4];
  float* out = (float*)d_out;

  // workspace layout (72 MB + 256 B)
  char* ws = (char*)d_ws;
  int* seg_off = (int*)ws;                                  // 136 B
  unsigned short* xb  = (unsigned short*)(ws + 256);        // 16 MB
  unsigned short* w1b = (unsigned short*)(ws + 256 + (16u << 20));
  unsigned short* w2b = (unsigned short*)(ws + 256 + (32u << 20));
  unsigned short* w3b = (unsigned short*)(ws + 256 + (48u << 20));
  unsigned short* hb  = (unsigned short*)(ws + 256 + (64u << 20));  // 8 MB

  convert4_kernel<<<dim3(2048, 4), 256, 0, stream>>>(
      x, w1, w2, w3, (ull*)xb, (ull*)w1b, (ull*)w2b, (ull*)w3b);
  setup_kernel<<<dim3(Bq), 64, 0, stream>>>(counts, seg_off);
  gemm1_kernel<<<dim3(HIDq / 64, Mq / 128), 256, 0, stream>>>(xb, w1b, w3b, seg_off, hb);
  gemm2_kernel<<<dim3(DIMq / 128, Mq / 128), 256, 0, stream>>>(hb, w2b, seg_off, out);
}

// Round 5
// 288.822 us; speedup vs baseline: 1.2160x; 1.0793x over previous
//
#include <hip/hip_runtime.h>
#include <hip/hip_bf16.h>
#include <stdint.h>

// Problem constants (match reference)
#define Bq   2
#define Tq   4096
#define DIMq 1024
#define HIDq 512
#define Eq   16
#define Mq   (Bq * Tq)   // 8192 flattened token rows

typedef __attribute__((ext_vector_type(8))) short bf16x8;   // 8 bf16 = 4 VGPRs
typedef __attribute__((ext_vector_type(4))) float f32x4;
typedef unsigned long long ull;

// --- bf16 helpers (RNE, matches XLA rounding) ---
__device__ __forceinline__ unsigned int f2bf(float f) {
  unsigned int u = __builtin_bit_cast(unsigned int, f);
  return (u + 0x7FFFu + ((u >> 16) & 1u)) >> 16;
}
__device__ __forceinline__ float bf2f(unsigned int s) {
  unsigned int u = s << 16;
  return __builtin_bit_cast(float, u);
}
__device__ __forceinline__ ull pack4(const float4 v) {
  return (ull)f2bf(v.x)
       | ((ull)f2bf(v.y) << 16)
       | ((ull)f2bf(v.z) << 32)
       | ((ull)f2bf(v.w) << 48);
}

// async global->LDS, 16B per lane; lds ptr must be WAVE-UNIFORM base (HW adds lane*16)
#define GLOAD16(gp, lp)                                                        \
  __builtin_amdgcn_global_load_lds(                                            \
      (const __attribute__((address_space(1))) unsigned int*)(gp),             \
      (__attribute__((address_space(3))) unsigned int*)(lp), 16, 0, 0)

// ---------------------------------------------------------------------------
// Kernel A: fp32 -> bf16 conversion for x, w1, w2, w3 (each 8,388,608 floats).
// ---------------------------------------------------------------------------
__global__ __launch_bounds__(256) void convert4_kernel(
    const float* __restrict__ x,  const float* __restrict__ w1,
    const float* __restrict__ w2, const float* __restrict__ w3,
    ull* __restrict__ xb, ull* __restrict__ w1b,
    ull* __restrict__ w2b, ull* __restrict__ w3b) {
  const float* s;
  ull* d;
  switch (blockIdx.y) {
    case 0:  s = x;  d = xb;  break;
    case 1:  s = w1; d = w1b; break;
    case 2:  s = w2; d = w2b; break;
    default: s = w3; d = w3b; break;
  }
  const int N4 = (8388608 / 4);
  for (int i = blockIdx.x * blockDim.x + threadIdx.x; i < N4;
       i += gridDim.x * blockDim.x) {
    float4 v = ((const float4*)s)[i];
    d[i] = pack4(v);
  }
}

// ---------------------------------------------------------------------------
// Kernel 0: per-batch exclusive cumsum of expert token counts.
// ---------------------------------------------------------------------------
__global__ void setup_kernel(const int* __restrict__ counts, int* __restrict__ seg_off) {
  int b = blockIdx.x;
  if (threadIdx.x == 0) {
    int s = 0;
    seg_off[b * (Eq + 1)] = 0;
    for (int e = 0; e < Eq; ++e) {
      s += counts[b * Eq + e];
      seg_off[b * (Eq + 1) + e + 1] = s;
    }
  }
}

// ---------------------------------------------------------------------------
// Kernel 1: h = bf16( silu(x.w1^T) * (x.w3^T) )
// 128m x 64n tile, BK=64, 4 waves. 2-deep pipelined double-buffered LDS:
// STAGE(t+1) issued BEFORE compute(t); one __syncthreads per K-step.
// LDS layout XOR-swizzled via pre-swizzled GLOBAL source (rule #21):
//   data(row, kc) stored at byte row*128 + ((kc*2) ^ ((row&7)<<4)).
// ---------------------------------------------------------------------------
__global__ __launch_bounds__(256) void gemm1_kernel(
    const unsigned short* __restrict__ xb, const unsigned short* __restrict__ w1b,
    const unsigned short* __restrict__ w3b, const int* __restrict__ seg_off,
    unsigned short* __restrict__ hbuf) {
  const int nt  = blockIdx.x;           // 0..7  (HID/64)
  const int mt  = blockIdx.y;           // 0..63 (M/128)
  const int t0  = mt * 128;
  const int n0  = nt * 64;
  const int b   = t0 >> 12;
  const int tl0 = t0 & (Tq - 1);

  __shared__ unsigned short As[2][128 * 64];   // 2 x 16 KB
  __shared__ unsigned short W1s[2][64 * 64];   // 2 x 8 KB
  __shared__ unsigned short W3s[2][64 * 64];   // 2 x 8 KB   (total 64 KB)

  const int tid  = threadIdx.x;
  const int lane = tid & 63;
  const int wv   = tid >> 6;
  const int wm2  = (wv >> 1) * 64;      // wave m-offset (0/64)
  const int wn2  = (wv & 1) * 32;       // wave n-offset (0/32)
  const int q    = lane >> 4;
  const int l15  = lane & 15;
  const int rsw  = (l15 & 7) << 4;      // read-side swizzle (row&7)<<4

  #pragma unroll 1
  for (int e = 0; e < Eq; ++e) {
    const int lo = seg_off[b * (Eq + 1) + e];
    const int hi = seg_off[b * (Eq + 1) + e + 1];
    const int s  = lo > tl0 ? lo : tl0;
    const int en = hi < tl0 + 128 ? hi : tl0 + 128;
    if (s >= en) continue;

    const unsigned short* __restrict__ w1e = w1b + (size_t)e * HIDq * DIMq;
    const unsigned short* __restrict__ w3e = w3b + (size_t)e * HIDq * DIMq;

    f32x4 acc1[4][2], acc3[4][2];
    #pragma unroll
    for (int i = 0; i < 4; ++i)
      #pragma unroll
      for (int j = 0; j < 2; ++j) { acc1[i][j] = (f32x4)0.f; acc3[i][j] = (f32x4)0.f; }

    auto stage = [&](int k0, int bi) {
      #pragma unroll
      for (int it = 0; it < 4; ++it) {                     // A: 128x64 bf16
        const int c = it * 256 + tid;
        const int row = c >> 3;
        const int kc = ((c & 7) << 3) ^ ((row & 7) << 3);  // pre-swizzled source col
        GLOAD16(xb + (size_t)(t0 + row) * DIMq + k0 + kc,
                (char*)&As[bi][0] + it * 4096 + wv * 1024);
      }
      #pragma unroll
      for (int it = 0; it < 2; ++it) {                     // W1,W3: 64x64 each
        const int c = it * 256 + tid;
        const int row = c >> 3;
        const int kc = ((c & 7) << 3) ^ ((row & 7) << 3);
        GLOAD16(w1e + (size_t)(n0 + row) * DIMq + k0 + kc,
                (char*)&W1s[bi][0] + it * 4096 + wv * 1024);
        GLOAD16(w3e + (size_t)(n0 + row) * DIMq + k0 + kc,
                (char*)&W3s[bi][0] + it * 4096 + wv * 1024);
      }
    };
    auto compute = [&](int bi) {
      const char* Ab = (const char*)&As[bi][0];
      const char* Ub = (const char*)&W1s[bi][0];
      const char* Vb = (const char*)&W3s[bi][0];
      #pragma unroll
      for (int ks = 0; ks < 2; ++ks) {
        const int kb = (ks * 64 + q * 16) ^ rsw;           // swizzled read col
        bf16x8 a[4], u[2], v[2];
        #pragma unroll
        for (int i = 0; i < 4; ++i)
          a[i] = *(const bf16x8*)(Ab + (wm2 + i * 16 + l15) * 128 + kb);
        #pragma unroll
        for (int j = 0; j < 2; ++j) {
          u[j] = *(const bf16x8*)(Ub + (wn2 + j * 16 + l15) * 128 + kb);
          v[j] = *(const bf16x8*)(Vb + (wn2 + j * 16 + l15) * 128 + kb);
        }
        #pragma unroll
        for (int i = 0; i < 4; ++i)
          #pragma unroll
          for (int j = 0; j < 2; ++j) {
            acc1[i][j] = __builtin_amdgcn_mfma_f32_16x16x32_bf16(a[i], u[j], acc1[i][j], 0, 0, 0);
            acc3[i][j] = __builtin_amdgcn_mfma_f32_16x16x32_bf16(a[i], v[j], acc3[i][j], 0, 0, 0);
          }
      }
    };

    stage(0, 0);
    __syncthreads();                     // drains vmcnt(0): buf0 ready
    int cur = 0;
    #pragma unroll 1
    for (int k0 = 0; k0 < DIMq; k0 += 64) {
      if (k0 + 64 < DIMq) stage(k0 + 64, cur ^ 1);   // issue next tile FIRST
      compute(cur);                                  // MFMA hides load latency
      __syncthreads();                               // vmcnt(0): next buf ready; cur free
      cur ^= 1;
    }

    // ---- epilogue: SwiGLU with reference-matching bf16 roundings ----
    const int rlo = s - tl0, rhi = en - tl0;
    #pragma unroll
    for (int i = 0; i < 4; ++i)
      #pragma unroll
      for (int j = 0; j < 2; ++j)
        #pragma unroll
        for (int rr = 0; rr < 4; ++rr) {
          const int row = wm2 + i * 16 + q * 4 + rr;
          if (row >= rlo && row < rhi) {
            const float aa = bf2f(f2bf(acc1[i][j][rr]));
            const float cc = bf2f(f2bf(acc3[i][j][rr]));
            const float sg = bf2f(f2bf(1.f / (1.f + __expf(-aa))));
            const float tt = bf2f(f2bf(aa * sg));
            hbuf[(size_t)(t0 + row) * HIDq + n0 + wn2 + j * 16 + l15] =
                (unsigned short)f2bf(tt * cc);
          }
        }
  }
}

// ---------------------------------------------------------------------------
// Kernel 2: out = f32( bf16( h . w2^T ) ).  128m x 128n, BK=64, same pipeline.
// ---------------------------------------------------------------------------
__global__ __launch_bounds__(256) void gemm2_kernel(
    const unsigned short* __restrict__ hb, const unsigned short* __restrict__ w2b,
    const int* __restrict__ seg_off, float* __restrict__ out) {
  const int nt  = blockIdx.x;           // 0..7 (DIM/128)
  const int mt  = blockIdx.y;           // 0..63
  const int t0  = mt * 128;
  const int n0  = nt * 128;
  const int b   = t0 >> 12;
  const int tl0 = t0 & (Tq - 1);

  __shared__ unsigned short Hs[2][128 * 64];   // 2 x 16 KB
  __shared__ unsigned short Bs[2][128 * 64];   // 2 x 16 KB  (total 64 KB)

  const int tid  = threadIdx.x;
  const int lane = tid & 63;
  const int wv   = tid >> 6;
  const int wm2  = (wv >> 1) * 64;
  const int wn2  = (wv & 1) * 64;
  const int q    = lane >> 4;
  const int l15  = lane & 15;
  const int rsw  = (l15 & 7) << 4;

  #pragma unroll 1
  for (int e = 0; e < Eq; ++e) {
    const int lo = seg_off[b * (Eq + 1) + e];
    const int hi = seg_off[b * (Eq + 1) + e + 1];
    const int s  = lo > tl0 ? lo : tl0;
    const int en = hi < tl0 + 128 ? hi : tl0 + 128;
    if (s >= en) continue;

    const unsigned short* __restrict__ w2e = w2b + (size_t)e * DIMq * HIDq;

    f32x4 acc[4][4];
    #pragma unroll
    for (int i = 0; i < 4; ++i)
      #pragma unroll
      for (int j = 0; j < 4; ++j) acc[i][j] = (f32x4)0.f;

    auto stage = [&](int k0, int bi) {
      #pragma unroll
      for (int it = 0; it < 4; ++it) {
        const int c = it * 256 + tid;
        const int row = c >> 3;
        const int kc = ((c & 7) << 3) ^ ((row & 7) << 3);
        GLOAD16(hb + (size_t)(t0 + row) * HIDq + k0 + kc,
                (char*)&Hs[bi][0] + it * 4096 + wv * 1024);
        GLOAD16(w2e + (size_t)(n0 + row) * HIDq + k0 + kc,
                (char*)&Bs[bi][0] + it * 4096 + wv * 1024);
      }
    };
    auto compute = [&](int bi) {
      const char* Ab = (const char*)&Hs[bi][0];
      const char* Wb = (const char*)&Bs[bi][0];
      #pragma unroll
      for (int ks = 0; ks < 2; ++ks) {
        const int kb = (ks * 64 + q * 16) ^ rsw;
        bf16x8 a[4], w[4];
        #pragma unroll
        for (int i = 0; i < 4; ++i) {
          a[i] = *(const bf16x8*)(Ab + (wm2 + i * 16 + l15) * 128 + kb);
          w[i] = *(const bf16x8*)(Wb + (wn2 + i * 16 + l15) * 128 + kb);
        }
        #pragma unroll
        for (int i = 0; i < 4; ++i)
          #pragma unroll
          for (int j = 0; j < 4; ++j)
            acc[i][j] = __builtin_amdgcn_mfma_f32_16x16x32_bf16(a[i], w[j], acc[i][j], 0, 0, 0);
      }
    };

    stage(0, 0);
    __syncthreads();
    int cur = 0;
    #pragma unroll 1
    for (int k0 = 0; k0 < HIDq; k0 += 64) {
      if (k0 + 64 < HIDq) stage(k0 + 64, cur ^ 1);
      compute(cur);
      __syncthreads();
      cur ^= 1;
    }

    const int rlo = s - tl0, rhi = en - tl0;
    #pragma unroll
    for (int i = 0; i < 4; ++i)
      #pragma unroll
      for (int j = 0; j < 4; ++j)
        #pragma unroll
        for (int rr = 0; rr < 4; ++rr) {
          const int row = wm2 + i * 16 + q * 4 + rr;
          if (row >= rlo && row < rhi) {
            out[(size_t)(t0 + row) * DIMq + n0 + wn2 + j * 16 + l15] =
                bf2f(f2bf(acc[i][j][rr]));   // reference rounds y to bf16
          }
        }
  }
}

// ---------------------------------------------------------------------------
extern "C" void kernel_launch(void* const* d_in, const int* in_sizes, int n_in,
                              void* d_out, int out_size, void* d_ws, size_t ws_size,
                              hipStream_t stream) {
  const float* x      = (const float*)d_in[0];
  const int*   counts = (const int*)d_in[1];
  const float* w1     = (const float*)d_in[2];
  const float* w2     = (const float*)d_in[3];
  const float* w3     = (const float*)d_in[4];
  float* out = (float*)d_out;

  // workspace layout (72 MB + 256 B)
  char* ws = (char*)d_ws;
  int* seg_off = (int*)ws;                                  // 136 B
  unsigned short* xb  = (unsigned short*)(ws + 256);        // 16 MB
  unsigned short* w1b = (unsigned short*)(ws + 256 + (16u << 20));
  unsigned short* w2b = (unsigned short*)(ws + 256 + (32u << 20));
  unsigned short* w3b = (unsigned short*)(ws + 256 + (48u << 20));
  unsigned short* hb  = (unsigned short*)(ws + 256 + (64u << 20));  // 8 MB

  convert4_kernel<<<dim3(2048, 4), 256, 0, stream>>>(
      x, w1, w2, w3, (ull*)xb, (ull*)w1b, (ull*)w2b, (ull*)w3b);
  setup_kernel<<<dim3(Bq), 64, 0, stream>>>(counts, seg_off);
  gemm1_kernel<<<dim3(HIDq / 64, Mq / 128), 256, 0, stream>>>(xb, w1b, w3b, seg_off, hb);
  gemm2_kernel<<<dim3(DIMq / 128, Mq / 128), 256, 0, stream>>>(hb, w2b, seg_off, out);
}

// Round 7
// 280.666 us; speedup vs baseline: 1.2514x; 1.0291x over previous
//
#include <hip/hip_runtime.h>
#include <hip/hip_bf16.h>
#include <stdint.h>

// Problem constants (match reference)
#define Bq   2
#define Tq   4096
#define DIMq 1024
#define HIDq 512
#define Eq   16
#define Mq   (Bq * Tq)   // 8192 flattened token rows

typedef __attribute__((ext_vector_type(8))) short bf16x8;   // 8 bf16 = 4 VGPRs
typedef __attribute__((ext_vector_type(4))) float f32x4;
typedef unsigned long long ull;

// --- bf16 helpers (RNE, matches XLA rounding) ---
__device__ __forceinline__ unsigned int f2bf(float f) {
  unsigned int u = __builtin_bit_cast(unsigned int, f);
  return (u + 0x7FFFu + ((u >> 16) & 1u)) >> 16;
}
__device__ __forceinline__ float bf2f(unsigned int s) {
  unsigned int u = s << 16;
  return __builtin_bit_cast(float, u);
}
__device__ __forceinline__ ull pack4(const float4 v) {
  return (ull)f2bf(v.x)
       | ((ull)f2bf(v.y) << 16)
       | ((ull)f2bf(v.z) << 32)
       | ((ull)f2bf(v.w) << 48);
}

// async global->LDS, 16B per lane; lds ptr must be WAVE-UNIFORM base (HW adds lane*16)
#define GLOAD16(gp, lp)                                                        \
  __builtin_amdgcn_global_load_lds(                                            \
      (const __attribute__((address_space(1))) unsigned int*)(gp),             \
      (__attribute__((address_space(3))) unsigned int*)(lp), 16, 0, 0)

// ---------------------------------------------------------------------------
// Kernel A: fp32 -> bf16 conversion for x, w1, w2, w3 (each 8,388,608 floats).
// ---------------------------------------------------------------------------
__global__ __launch_bounds__(256) void convert4_kernel(
    const float* __restrict__ x,  const float* __restrict__ w1,
    const float* __restrict__ w2, const float* __restrict__ w3,
    ull* __restrict__ xb, ull* __restrict__ w1b,
    ull* __restrict__ w2b, ull* __restrict__ w3b) {
  const float* s;
  ull* d;
  switch (blockIdx.y) {
    case 0:  s = x;  d = xb;  break;
    case 1:  s = w1; d = w1b; break;
    case 2:  s = w2; d = w2b; break;
    default: s = w3; d = w3b; break;
  }
  const int N4 = (8388608 / 4);
  for (int i = blockIdx.x * blockDim.x + threadIdx.x; i < N4;
       i += gridDim.x * blockDim.x) {
    float4 v = ((const float4*)s)[i];
    d[i] = pack4(v);
  }
}

// ---------------------------------------------------------------------------
// Kernel 0: per-batch exclusive cumsum of expert token counts.
// ---------------------------------------------------------------------------
__global__ void setup_kernel(const int* __restrict__ counts, int* __restrict__ seg_off) {
  int b = blockIdx.x;
  if (threadIdx.x == 0) {
    int s = 0;
    seg_off[b * (Eq + 1)] = 0;
    for (int e = 0; e < Eq; ++e) {
      s += counts[b * Eq + e];
      seg_off[b * (Eq + 1) + e + 1] = s;
    }
  }
}

// XCD-chunked decode: HW maps bid%8 -> XCD (m09). Chunk c owns mt in
// [8c, 8c+8) x all n-tiles, so the 8 blocks sharing an x/h panel hit the
// SAME XCD's L2 (panel set = 2MB < 4MB L2). 512 = 8 chunks x 64 blocks
// = exactly one XCD residency round (2 blocks/CU x 32 CU). Bijective.
__device__ __forceinline__ void chunk_decode(int bid, int& mt, int& nt) {
  const int c = bid & 7;
  const int k = bid >> 3;        // 0..63
  mt = c * 8 + (k >> 3);
  nt = k & 7;
}

// ---------------------------------------------------------------------------
// Kernel 1: h = bf16( silu(x.w1^T) * (x.w3^T) )
// 128m x 64n tile, BK=64, 4 waves, double-buffered LDS, stage-before-compute.
// LDS XOR-swizzled via pre-swizzled GLOBAL source + matching read XOR.
// ---------------------------------------------------------------------------
__global__ __launch_bounds__(256) void gemm1_kernel(
    const unsigned short* __restrict__ xb, const unsigned short* __restrict__ w1b,
    const unsigned short* __restrict__ w3b, const int* __restrict__ seg_off,
    unsigned short* __restrict__ hbuf) {
  int mt, nt;
  chunk_decode(blockIdx.x, mt, nt);
  const int t0  = mt * 128;
  const int n0  = nt * 64;
  const int b   = t0 >> 12;
  const int tl0 = t0 & (Tq - 1);

  __shared__ unsigned short As[2][128 * 64];   // 2 x 16 KB
  __shared__ unsigned short W1s[2][64 * 64];   // 2 x 8 KB
  __shared__ unsigned short W3s[2][64 * 64];   // 2 x 8 KB   (total 64 KB)

  const int tid  = threadIdx.x;
  const int lane = tid & 63;
  const int wv   = tid >> 6;
  const int wm2  = (wv >> 1) * 64;      // wave m-offset (0/64)
  const int wn2  = (wv & 1) * 32;       // wave n-offset (0/32)
  const int q    = lane >> 4;
  const int l15  = lane & 15;
  const int rsw  = (l15 & 7) << 4;      // read-side swizzle (row&7)<<4

  #pragma unroll 1
  for (int e = 0; e < Eq; ++e) {
    const int lo = seg_off[b * (Eq + 1) + e];
    const int hi = seg_off[b * (Eq + 1) + e + 1];
    const int s  = lo > tl0 ? lo : tl0;
    const int en = hi < tl0 + 128 ? hi : tl0 + 128;
    if (s >= en) continue;

    const unsigned short* __restrict__ w1e = w1b + (size_t)e * HIDq * DIMq;
    const unsigned short* __restrict__ w3e = w3b + (size_t)e * HIDq * DIMq;

    f32x4 acc1[4][2], acc3[4][2];
    #pragma unroll
    for (int i = 0; i < 4; ++i)
      #pragma unroll
      for (int j = 0; j < 2; ++j) { acc1[i][j] = (f32x4)0.f; acc3[i][j] = (f32x4)0.f; }

    auto stage = [&](int k0, int bi) {
      #pragma unroll
      for (int it = 0; it < 4; ++it) {                     // A: 128x64 bf16
        const int c = it * 256 + tid;
        const int row = c >> 3;
        const int kc = ((c & 7) << 3) ^ ((row & 7) << 3);  // pre-swizzled source col
        GLOAD16(xb + (size_t)(t0 + row) * DIMq + k0 + kc,
                (char*)&As[bi][0] + it * 4096 + wv * 1024);
      }
      #pragma unroll
      for (int it = 0; it < 2; ++it) {                     // W1,W3: 64x64 each
        const int c = it * 256 + tid;
        const int row = c >> 3;
        const int kc = ((c & 7) << 3) ^ ((row & 7) << 3);
        GLOAD16(w1e + (size_t)(n0 + row) * DIMq + k0 + kc,
                (char*)&W1s[bi][0] + it * 4096 + wv * 1024);
        GLOAD16(w3e + (size_t)(n0 + row) * DIMq + k0 + kc,
                (char*)&W3s[bi][0] + it * 4096 + wv * 1024);
      }
    };
    auto compute = [&](int bi) {
      const char* Ab = (const char*)&As[bi][0];
      const char* Ub = (const char*)&W1s[bi][0];
      const char* Vb = (const char*)&W3s[bi][0];
      #pragma unroll
      for (int ks = 0; ks < 2; ++ks) {
        const int kb = (ks * 64 + q * 16) ^ rsw;           // swizzled read col
        bf16x8 a[4], u[2], v[2];
        #pragma unroll
        for (int i = 0; i < 4; ++i)
          a[i] = *(const bf16x8*)(Ab + (wm2 + i * 16 + l15) * 128 + kb);
        #pragma unroll
        for (int j = 0; j < 2; ++j) {
          u[j] = *(const bf16x8*)(Ub + (wn2 + j * 16 + l15) * 128 + kb);
          v[j] = *(const bf16x8*)(Vb + (wn2 + j * 16 + l15) * 128 + kb);
        }
        #pragma unroll
        for (int i = 0; i < 4; ++i)
          #pragma unroll
          for (int j = 0; j < 2; ++j) {
            acc1[i][j] = __builtin_amdgcn_mfma_f32_16x16x32_bf16(a[i], u[j], acc1[i][j], 0, 0, 0);
            acc3[i][j] = __builtin_amdgcn_mfma_f32_16x16x32_bf16(a[i], v[j], acc3[i][j], 0, 0, 0);
          }
      }
    };

    stage(0, 0);
    __syncthreads();                     // drains vmcnt(0): buf0 ready
    int cur = 0;
    #pragma unroll 1
    for (int k0 = 0; k0 < DIMq; k0 += 64) {
      if (k0 + 64 < DIMq) stage(k0 + 64, cur ^ 1);   // issue next tile FIRST
      compute(cur);                                  // MFMA hides load latency
      __syncthreads();                               // vmcnt(0): next buf ready; cur free
      cur ^= 1;
    }

    // ---- epilogue: SwiGLU with reference-matching bf16 roundings ----
    const int rlo = s - tl0, rhi = en - tl0;
    #pragma unroll
    for (int i = 0; i < 4; ++i)
      #pragma unroll
      for (int j = 0; j < 2; ++j)
        #pragma unroll
        for (int rr = 0; rr < 4; ++rr) {
          const int row = wm2 + i * 16 + q * 4 + rr;
          if (row >= rlo && row < rhi) {
            const float aa = bf2f(f2bf(acc1[i][j][rr]));
            const float cc = bf2f(f2bf(acc3[i][j][rr]));
            const float sg = bf2f(f2bf(1.f / (1.f + __expf(-aa))));
            const float tt = bf2f(f2bf(aa * sg));
            hbuf[(size_t)(t0 + row) * HIDq + n0 + wn2 + j * 16 + l15] =
                (unsigned short)f2bf(tt * cc);
          }
        }
  }
}

// ---------------------------------------------------------------------------
// Kernel 2: out = f32( bf16( h . w2^T ) ).  128m x 128n, BK=64, same pipeline.
// ---------------------------------------------------------------------------
__global__ __launch_bounds__(256) void gemm2_kernel(
    const unsigned short* __restrict__ hb, const unsigned short* __restrict__ w2b,
    const int* __restrict__ seg_off, float* __restrict__ out) {
  int mt, nt;
  chunk_decode(blockIdx.x, mt, nt);
  const int t0  = mt * 128;
  const int n0  = nt * 128;
  const int b   = t0 >> 12;
  const int tl0 = t0 & (Tq - 1);

  __shared__ unsigned short Hs[2][128 * 64];   // 2 x 16 KB
  __shared__ unsigned short Bs[2][128 * 64];   // 2 x 16 KB  (total 64 KB)

  const int tid  = threadIdx.x;
  const int lane = tid & 63;
  const int wv   = tid >> 6;
  const int wm2  = (wv >> 1) * 64;
  const int wn2  = (wv & 1) * 64;
  const int q    = lane >> 4;
  const int l15  = lane & 15;
  const int rsw  = (l15 & 7) << 4;

  #pragma unroll 1
  for (int e = 0; e < Eq; ++e) {
    const int lo = seg_off[b * (Eq + 1) + e];
    const int hi = seg_off[b * (Eq + 1) + e + 1];
    const int s  = lo > tl0 ? lo : tl0;
    const int en = hi < tl0 + 128 ? hi : tl0 + 128;
    if (s >= en) continue;

    const unsigned short* __restrict__ w2e = w2b + (size_t)e * DIMq * HIDq;

    f32x4 acc[4][4];
    #pragma unroll
    for (int i = 0; i < 4; ++i)
      #pragma unroll
      for (int j = 0; j < 4; ++j) acc[i][j] = (f32x4)0.f;

    auto stage = [&](int k0, int bi) {
      #pragma unroll
      for (int it = 0; it < 4; ++it) {
        const int c = it * 256 + tid;
        const int row = c >> 3;
        const int kc = ((c & 7) << 3) ^ ((row & 7) << 3);
        GLOAD16(hb + (size_t)(t0 + row) * HIDq + k0 + kc,
                (char*)&Hs[bi][0] + it * 4096 + wv * 1024);
        GLOAD16(w2e + (size_t)(n0 + row) * HIDq + k0 + kc,
                (char*)&Bs[bi][0] + it * 4096 + wv * 1024);
      }
    };
    auto compute = [&](int bi) {
      const char* Ab = (const char*)&Hs[bi][0];
      const char* Wb = (const char*)&Bs[bi][0];
      #pragma unroll
      for (int ks = 0; ks < 2; ++ks) {
        const int kb = (ks * 64 + q * 16) ^ rsw;
        bf16x8 a[4], w[4];
        #pragma unroll
        for (int i = 0; i < 4; ++i) {
          a[i] = *(const bf16x8*)(Ab + (wm2 + i * 16 + l15) * 128 + kb);
          w[i] = *(const bf16x8*)(Wb + (wn2 + i * 16 + l15) * 128 + kb);
        }
        #pragma unroll
        for (int i = 0; i < 4; ++i)
          #pragma unroll
          for (int j = 0; j < 4; ++j)
            acc[i][j] = __builtin_amdgcn_mfma_f32_16x16x32_bf16(a[i], w[j], acc[i][j], 0, 0, 0);
      }
    };

    stage(0, 0);
    __syncthreads();
    int cur = 0;
    #pragma unroll 1
    for (int k0 = 0; k0 < HIDq; k0 += 64) {
      if (k0 + 64 < HIDq) stage(k0 + 64, cur ^ 1);
      compute(cur);
      __syncthreads();
      cur ^= 1;
    }

    const int rlo = s - tl0, rhi = en - tl0;
    #pragma unroll
    for (int i = 0; i < 4; ++i)
      #pragma unroll
      for (int j = 0; j < 4; ++j)
        #pragma unroll
        for (int rr = 0; rr < 4; ++rr) {
          const int row = wm2 + i * 16 + q * 4 + rr;
          if (row >= rlo && row < rhi) {
            out[(size_t)(t0 + row) * DIMq + n0 + wn2 + j * 16 + l15] =
                bf2f(f2bf(acc[i][j][rr]));   // reference rounds y to bf16
          }
        }
  }
}

// ---------------------------------------------------------------------------
extern "C" void kernel_launch(void* const* d_in, const int* in_sizes, int n_in,
                              void* d_out, int out_size, void* d_ws, size_t ws_size,
                              hipStream_t stream) {
  const float* x      = (const float*)d_in[0];
  const int*   counts = (const int*)d_in[1];
  const float* w1     = (const float*)d_in[2];
  const float* w2     = (const float*)d_in[3];
  const float* w3     = (const float*)d_in[4];
  float* out = (float*)d_out;

  // workspace layout (72 MB + 256 B)
  char* ws = (char*)d_ws;
  int* seg_off = (int*)ws;                                  // 136 B
  unsigned short* xb  = (unsigned short*)(ws + 256);        // 16 MB
  unsigned short* w1b = (unsigned short*)(ws + 256 + (16u << 20));
  unsigned short* w2b = (unsigned short*)(ws + 256 + (32u << 20));
  unsigned short* w3b = (unsigned short*)(ws + 256 + (48u << 20));
  unsigned short* hb  = (unsigned short*)(ws + 256 + (64u << 20));  // 8 MB

  convert4_kernel<<<dim3(2048, 4), 256, 0, stream>>>(
      x, w1, w2, w3, (ull*)xb, (ull*)w1b, (ull*)w2b, (ull*)w3b);
  setup_kernel<<<dim3(Bq), 64, 0, stream>>>(counts, seg_off);
  gemm1_kernel<<<512, 256, 0, stream>>>(xb, w1b, w3b, seg_off, hb);
  gemm2_kernel<<<512, 256, 0, stream>>>(hb, w2b, seg_off, out);
}

// Round 8
// 262.342 us; speedup vs baseline: 1.3388x; 1.0698x over previous
//
#include <hip/hip_runtime.h>
#include <hip/hip_bf16.h>
#include <stdint.h>

// Problem constants (match reference)
#define Bq   2
#define Tq   4096
#define DIMq 1024
#define HIDq 512
#define Eq   16
#define Mq   (Bq * Tq)   // 8192 flattened token rows

typedef __attribute__((ext_vector_type(8))) short bf16x8;   // 8 bf16 = 4 VGPRs
typedef __attribute__((ext_vector_type(4))) float f32x4;
typedef unsigned long long ull;

// --- bf16 helpers (RNE, matches XLA rounding) ---
__device__ __forceinline__ unsigned int f2bf(float f) {
  unsigned int u = __builtin_bit_cast(unsigned int, f);
  return (u + 0x7FFFu + ((u >> 16) & 1u)) >> 16;
}
__device__ __forceinline__ float bf2f(unsigned int s) {
  unsigned int u = s << 16;
  return __builtin_bit_cast(float, u);
}
__device__ __forceinline__ ull pack4(const float4 v) {
  return (ull)f2bf(v.x)
       | ((ull)f2bf(v.y) << 16)
       | ((ull)f2bf(v.z) << 32)
       | ((ull)f2bf(v.w) << 48);
}

// async global->LDS, 16B per lane; lds ptr must be WAVE-UNIFORM base (HW adds lane*16)
#define GLOAD16(gp, lp)                                                        \
  __builtin_amdgcn_global_load_lds(                                            \
      (const __attribute__((address_space(1))) unsigned int*)(gp),             \
      (__attribute__((address_space(3))) unsigned int*)(lp), 16, 0, 0)

// ---------------------------------------------------------------------------
// Kernel A: fp32 -> bf16 conversion for x, w1, w2, w3 (each 8,388,608 floats).
// ---------------------------------------------------------------------------
__global__ __launch_bounds__(256) void convert4_kernel(
    const float* __restrict__ x,  const float* __restrict__ w1,
    const float* __restrict__ w2, const float* __restrict__ w3,
    ull* __restrict__ xb, ull* __restrict__ w1b,
    ull* __restrict__ w2b, ull* __restrict__ w3b) {
  const float* s;
  ull* d;
  switch (blockIdx.y) {
    case 0:  s = x;  d = xb;  break;
    case 1:  s = w1; d = w1b; break;
    case 2:  s = w2; d = w2b; break;
    default: s = w3; d = w3b; break;
  }
  const int N4 = (8388608 / 4);
  for (int i = blockIdx.x * blockDim.x + threadIdx.x; i < N4;
       i += gridDim.x * blockDim.x) {
    float4 v = ((const float4*)s)[i];
    d[i] = pack4(v);
  }
}

// XCD-chunked decode: HW maps bid%8 -> XCD (m09). Chunk c owns mt in
// [8c, 8c+8) x all n-tiles, so the 8 blocks sharing an x/h panel hit the
// SAME XCD's L2. Bijective for 512 = 8 x 64.
__device__ __forceinline__ void chunk_decode(int bid, int& mt, int& nt) {
  const int c = bid & 7;
  const int k = bid >> 3;        // 0..63
  mt = c * 8 + (k >> 3);
  nt = k & 7;
}

// ---------------------------------------------------------------------------
// Kernel 1: h = bf16( silu(x.w1^T) * (x.w3^T) )
// 128m x 64n tile, BK=64, EIGHT waves (512 thr) for TLP: wave tile 32x32,
// double-buffered LDS, stage-before-compute, XOR-swizzled (both sides).
// Expert segment bounds computed inline from counts (no setup kernel).
// ---------------------------------------------------------------------------
__global__ __launch_bounds__(512) void gemm1_kernel(
    const unsigned short* __restrict__ xb, const unsigned short* __restrict__ w1b,
    const unsigned short* __restrict__ w3b, const int* __restrict__ counts,
    unsigned short* __restrict__ hbuf) {
  int mt, nt;
  chunk_decode(blockIdx.x, mt, nt);
  const int t0  = mt * 128;
  const int n0  = nt * 64;
  const int b   = t0 >> 12;
  const int tl0 = t0 & (Tq - 1);

  __shared__ unsigned short As[2][128 * 64];   // 2 x 16 KB
  __shared__ unsigned short W1s[2][64 * 64];   // 2 x 8 KB
  __shared__ unsigned short W3s[2][64 * 64];   // 2 x 8 KB   (total 64 KB)

  const int tid  = threadIdx.x;
  const int lane = tid & 63;
  const int wv   = tid >> 6;            // 0..7
  const int wm2  = (wv >> 1) * 32;      // wave m-offset (0/32/64/96)
  const int wn2  = (wv & 1) * 32;       // wave n-offset (0/32)
  const int q    = lane >> 4;
  const int l15  = lane & 15;
  const int rsw  = (l15 & 7) << 4;      // read-side swizzle (row&7)<<4

  int lo = 0;
  #pragma unroll 1
  for (int e = 0; e < Eq; ++e) {
    const int hi = lo + counts[b * Eq + e];
    const int s  = lo > tl0 ? lo : tl0;
    const int en = hi < tl0 + 128 ? hi : tl0 + 128;
    lo = hi;
    if (s >= en) continue;

    const unsigned short* __restrict__ w1e = w1b + (size_t)e * HIDq * DIMq;
    const unsigned short* __restrict__ w3e = w3b + (size_t)e * HIDq * DIMq;

    f32x4 acc1[2][2], acc3[2][2];
    #pragma unroll
    for (int i = 0; i < 2; ++i)
      #pragma unroll
      for (int j = 0; j < 2; ++j) { acc1[i][j] = (f32x4)0.f; acc3[i][j] = (f32x4)0.f; }

    auto stage = [&](int k0, int bi) {
      #pragma unroll
      for (int it = 0; it < 2; ++it) {                     // A: 128x64 bf16
        const int c = it * 512 + tid;
        const int row = c >> 3;
        const int kc = ((c & 7) << 3) ^ ((row & 7) << 3);  // pre-swizzled source col
        GLOAD16(xb + (size_t)(t0 + row) * DIMq + k0 + kc,
                (char*)&As[bi][0] + it * 8192 + wv * 1024);
      }
      {                                                    // W1,W3: 64x64 each
        const int row = tid >> 3;
        const int kc = ((tid & 7) << 3) ^ ((row & 7) << 3);
        GLOAD16(w1e + (size_t)(n0 + row) * DIMq + k0 + kc,
                (char*)&W1s[bi][0] + wv * 1024);
        GLOAD16(w3e + (size_t)(n0 + row) * DIMq + k0 + kc,
                (char*)&W3s[bi][0] + wv * 1024);
      }
    };
    auto compute = [&](int bi) {
      const char* Ab = (const char*)&As[bi][0];
      const char* Ub = (const char*)&W1s[bi][0];
      const char* Vb = (const char*)&W3s[bi][0];
      #pragma unroll
      for (int ks = 0; ks < 2; ++ks) {
        const int kb = (ks * 64 + q * 16) ^ rsw;           // swizzled read col
        bf16x8 a[2], u[2], v[2];
        #pragma unroll
        for (int i = 0; i < 2; ++i)
          a[i] = *(const bf16x8*)(Ab + (wm2 + i * 16 + l15) * 128 + kb);
        #pragma unroll
        for (int j = 0; j < 2; ++j) {
          u[j] = *(const bf16x8*)(Ub + (wn2 + j * 16 + l15) * 128 + kb);
          v[j] = *(const bf16x8*)(Vb + (wn2 + j * 16 + l15) * 128 + kb);
        }
        #pragma unroll
        for (int i = 0; i < 2; ++i)
          #pragma unroll
          for (int j = 0; j < 2; ++j) {
            acc1[i][j] = __builtin_amdgcn_mfma_f32_16x16x32_bf16(a[i], u[j], acc1[i][j], 0, 0, 0);
            acc3[i][j] = __builtin_amdgcn_mfma_f32_16x16x32_bf16(a[i], v[j], acc3[i][j], 0, 0, 0);
          }
      }
    };

    stage(0, 0);
    __syncthreads();                     // buf0 ready
    int cur = 0;
    #pragma unroll 1
    for (int k0 = 0; k0 < DIMq; k0 += 64) {
      if (k0 + 64 < DIMq) stage(k0 + 64, cur ^ 1);   // issue next tile FIRST
      compute(cur);                                  // MFMA hides load latency
      __syncthreads();                               // next buf ready; cur free
      cur ^= 1;
    }

    // ---- epilogue: SwiGLU with reference-matching bf16 roundings ----
    const int rlo = s - tl0, rhi = en - tl0;
    #pragma unroll
    for (int i = 0; i < 2; ++i)
      #pragma unroll
      for (int j = 0; j < 2; ++j)
        #pragma unroll
        for (int rr = 0; rr < 4; ++rr) {
          const int row = wm2 + i * 16 + q * 4 + rr;
          if (row >= rlo && row < rhi) {
            const float aa = bf2f(f2bf(acc1[i][j][rr]));
            const float cc = bf2f(f2bf(acc3[i][j][rr]));
            const float sg = bf2f(f2bf(1.f / (1.f + __expf(-aa))));
            const float tt = bf2f(f2bf(aa * sg));
            hbuf[(size_t)(t0 + row) * HIDq + n0 + wn2 + j * 16 + l15] =
                (unsigned short)f2bf(tt * cc);
          }
        }
  }
}

// ---------------------------------------------------------------------------
// Kernel 2: out = f32( bf16( h . w2^T ) ).  128m x 128n, BK=64, 8 waves,
// wave tile 32x64 (acc[2][4]).
// ---------------------------------------------------------------------------
__global__ __launch_bounds__(512) void gemm2_kernel(
    const unsigned short* __restrict__ hb, const unsigned short* __restrict__ w2b,
    const int* __restrict__ counts, float* __restrict__ out) {
  int mt, nt;
  chunk_decode(blockIdx.x, mt, nt);
  const int t0  = mt * 128;
  const int n0  = nt * 128;
  const int b   = t0 >> 12;
  const int tl0 = t0 & (Tq - 1);

  __shared__ unsigned short Hs[2][128 * 64];   // 2 x 16 KB
  __shared__ unsigned short Bs[2][128 * 64];   // 2 x 16 KB  (total 64 KB)

  const int tid  = threadIdx.x;
  const int lane = tid & 63;
  const int wv   = tid >> 6;
  const int wm2  = (wv >> 1) * 32;      // 0/32/64/96
  const int wn2  = (wv & 1) * 64;       // 0/64
  const int q    = lane >> 4;
  const int l15  = lane & 15;
  const int rsw  = (l15 & 7) << 4;

  int lo = 0;
  #pragma unroll 1
  for (int e = 0; e < Eq; ++e) {
    const int hi = lo + counts[b * Eq + e];
    const int s  = lo > tl0 ? lo : tl0;
    const int en = hi < tl0 + 128 ? hi : tl0 + 128;
    lo = hi;
    if (s >= en) continue;

    const unsigned short* __restrict__ w2e = w2b + (size_t)e * DIMq * HIDq;

    f32x4 acc[2][4];
    #pragma unroll
    for (int i = 0; i < 2; ++i)
      #pragma unroll
      for (int j = 0; j < 4; ++j) acc[i][j] = (f32x4)0.f;

    auto stage = [&](int k0, int bi) {
      #pragma unroll
      for (int it = 0; it < 2; ++it) {
        const int c = it * 512 + tid;
        const int row = c >> 3;
        const int kc = ((c & 7) << 3) ^ ((row & 7) << 3);
        GLOAD16(hb + (size_t)(t0 + row) * HIDq + k0 + kc,
                (char*)&Hs[bi][0] + it * 8192 + wv * 1024);
        GLOAD16(w2e + (size_t)(n0 + row) * HIDq + k0 + kc,
                (char*)&Bs[bi][0] + it * 8192 + wv * 1024);
      }
    };
    auto compute = [&](int bi) {
      const char* Ab = (const char*)&Hs[bi][0];
      const char* Wb = (const char*)&Bs[bi][0];
      #pragma unroll
      for (int ks = 0; ks < 2; ++ks) {
        const int kb = (ks * 64 + q * 16) ^ rsw;
        bf16x8 a[2], w[4];
        #pragma unroll
        for (int i = 0; i < 2; ++i)
          a[i] = *(const bf16x8*)(Ab + (wm2 + i * 16 + l15) * 128 + kb);
        #pragma unroll
        for (int j = 0; j < 4; ++j)
          w[j] = *(const bf16x8*)(Wb + (wn2 + j * 16 + l15) * 128 + kb);
        #pragma unroll
        for (int i = 0; i < 2; ++i)
          #pragma unroll
          for (int j = 0; j < 4; ++j)
            acc[i][j] = __builtin_amdgcn_mfma_f32_16x16x32_bf16(a[i], w[j], acc[i][j], 0, 0, 0);
      }
    };

    stage(0, 0);
    __syncthreads();
    int cur = 0;
    #pragma unroll 1
    for (int k0 = 0; k0 < HIDq; k0 += 64) {
      if (k0 + 64 < HIDq) stage(k0 + 64, cur ^ 1);
      compute(cur);
      __syncthreads();
      cur ^= 1;
    }

    const int rlo = s - tl0, rhi = en - tl0;
    #pragma unroll
    for (int i = 0; i < 2; ++i)
      #pragma unroll
      for (int j = 0; j < 4; ++j)
        #pragma unroll
        for (int rr = 0; rr < 4; ++rr) {
          const int row = wm2 + i * 16 + q * 4 + rr;
          if (row >= rlo && row < rhi) {
            out[(size_t)(t0 + row) * DIMq + n0 + wn2 + j * 16 + l15] =
                bf2f(f2bf(acc[i][j][rr]));   // reference rounds y to bf16
          }
        }
  }
}

// ---------------------------------------------------------------------------
extern "C" void kernel_launch(void* const* d_in, const int* in_sizes, int n_in,
                              void* d_out, int out_size, void* d_ws, size_t ws_size,
                              hipStream_t stream) {
  const float* x      = (const float*)d_in[0];
  const int*   counts = (const int*)d_in[1];
  const float* w1     = (const float*)d_in[2];
  const float* w2     = (const float*)d_in[3];
  const float* w3     = (const float*)d_in[4];
  float* out = (float*)d_out;

  // workspace layout (72 MB + 256 B)
  char* ws = (char*)d_ws;
  unsigned short* xb  = (unsigned short*)(ws + 256);        // 16 MB
  unsigned short* w1b = (unsigned short*)(ws + 256 + (16u << 20));
  unsigned short* w2b = (unsigned short*)(ws + 256 + (32u << 20));
  unsigned short* w3b = (unsigned short*)(ws + 256 + (48u << 20));
  unsigned short* hb  = (unsigned short*)(ws + 256 + (64u << 20));  // 8 MB

  convert4_kernel<<<dim3(2048, 4), 256, 0, stream>>>(
      x, w1, w2, w3, (ull*)xb, (ull*)w1b, (ull*)w2b, (ull*)w3b);
  gemm1_kernel<<<512, 512, 0, stream>>>(xb, w1b, w3b, counts, hb);
  gemm2_kernel<<<512, 512, 0, stream>>>(hb, w2b, counts, out);
}

// Round 10
// 231.382 us; speedup vs baseline: 1.5179x; 1.1338x over previous
//
#include <hip/hip_runtime.h>
#include <hip/hip_bf16.h>
#include <stdint.h>

// Problem constants (match reference)
#define Bq   2
#define Tq   4096
#define DIMq 1024
#define HIDq 512
#define Eq   16
#define Mq   (Bq * Tq)   // 8192 flattened token rows

typedef __attribute__((ext_vector_type(8))) short bf16x8;   // 8 bf16 = 4 VGPRs
typedef __attribute__((ext_vector_type(4))) float f32x4;
typedef unsigned long long ull;

// --- bf16 helpers (RNE, matches XLA rounding) ---
__device__ __forceinline__ unsigned int f2bf(float f) {
  unsigned int u = __builtin_bit_cast(unsigned int, f);
  return (u + 0x7FFFu + ((u >> 16) & 1u)) >> 16;
}
__device__ __forceinline__ float bf2f(unsigned int s) {
  unsigned int u = s << 16;
  return __builtin_bit_cast(float, u);
}
__device__ __forceinline__ ull pack4(const float4 v) {
  return (ull)f2bf(v.x)
       | ((ull)f2bf(v.y) << 16)
       | ((ull)f2bf(v.z) << 32)
       | ((ull)f2bf(v.w) << 48);
}

// async global->LDS, 16B per lane; lds ptr must be WAVE-UNIFORM base (HW adds lane*16)
#define GLOAD16(gp, lp)                                                        \
  __builtin_amdgcn_global_load_lds(                                            \
      (const __attribute__((address_space(1))) unsigned int*)(gp),             \
      (__attribute__((address_space(3))) unsigned int*)(lp), 16, 0, 0)

// ---------------------------------------------------------------------------
// Kernel A: fp32 -> bf16 conversion for x, w1, w2, w3 (each 8,388,608 floats).
// ---------------------------------------------------------------------------
__global__ __launch_bounds__(256) void convert4_kernel(
    const float* __restrict__ x,  const float* __restrict__ w1,
    const float* __restrict__ w2, const float* __restrict__ w3,
    ull* __restrict__ xb, ull* __restrict__ w1b,
    ull* __restrict__ w2b, ull* __restrict__ w3b) {
  const float* s;
  ull* d;
  switch (blockIdx.y) {
    case 0:  s = x;  d = xb;  break;
    case 1:  s = w1; d = w1b; break;
    case 2:  s = w2; d = w2b; break;
    default: s = w3; d = w3b; break;
  }
  const int N4 = (8388608 / 4);
  for (int i = blockIdx.x * blockDim.x + threadIdx.x; i < N4;
       i += gridDim.x * blockDim.x) {
    float4 v = ((const float4*)s)[i];
    d[i] = pack4(v);
  }
}

// ---------------------------------------------------------------------------
// Kernel 0: build uniform worklist. One item = (mt, nt, e, rlo, rhi):
// one full K-run on one 128-row m-tile x one n-tile for one expert segment.
// Items sorted by mt (locality). Packed u32:
//   [29:24]=mt  [23:21]=nt  [19:16]=e  [15:8]=rlo  [7:0]=rhi
// wl[0] = N items; items at wl[1..].
// ---------------------------------------------------------------------------
__global__ void setup_worklist(const int* __restrict__ counts,
                               unsigned int* __restrict__ wl) {
  __shared__ int ns_arr[64];
  const int t   = threadIdx.x;          // m-tile id 0..63
  const int b   = t >> 5;
  const int tl0 = (t & 31) * 128;
  int se[16], sl[16], sh[16];
  int ns = 0, lo = 0;
  for (int e = 0; e < Eq; ++e) {
    const int hi = lo + counts[b * Eq + e];
    const int s  = lo > tl0 ? lo : tl0;
    const int en = hi < tl0 + 128 ? hi : tl0 + 128;
    if (s < en) { se[ns] = e; sl[ns] = s - tl0; sh[ns] = en - tl0; ++ns; }
    lo = hi;
  }
  ns_arr[t] = ns;
  __syncthreads();
  int off = 0;
  for (int i = 0; i < t; ++i) off += ns_arr[i];
  for (int k = 0; k < ns; ++k)
    for (int nt = 0; nt < 8; ++nt)
      wl[1 + (off + k) * 8 + nt] =
          ((unsigned int)t << 24) | ((unsigned int)nt << 21) |
          ((unsigned int)se[k] << 16) | ((unsigned int)sl[k] << 8) |
          (unsigned int)sh[k];
  if (t == 63) wl[0] = (unsigned int)((off + ns) * 8);
}

// XCD-sliced grid-stride: XCD c (= bid&7, per m09 bid%8->XCD) owns the
// contiguous worklist slice [c*q, (c+1)*q); block s=bid>>3 strides by 64
// inside the slice. mt-sorted list => slice shares x/h panels in one L2.
#define WORK_LOOP(wlptr)                                                       \
  const int Nw = (int)wlptr[0];                                                \
  const int qw = (Nw + 7) >> 3;                                                \
  const int cx = blockIdx.x & 7, sx = blockIdx.x >> 3;                         \
  const int jend = min((cx + 1) * qw, Nw);                                     \
  for (int j = cx * qw + sx; j < jend; j += 64)

// ---------------------------------------------------------------------------
// Kernel 1: h = bf16( silu(x.w1^T) * (x.w3^T) )
// Item: 128m x 64n, BK=64, 8 waves (wave tile 32x32), double-buffered LDS,
// stage-before-compute, XOR-swizzle via pre-swizzled global source.
// ---------------------------------------------------------------------------
__global__ __launch_bounds__(512) void gemm1_kernel(
    const unsigned short* __restrict__ xb, const unsigned short* __restrict__ w1b,
    const unsigned short* __restrict__ w3b, const unsigned int* __restrict__ wl,
    unsigned short* __restrict__ hbuf) {
  __shared__ unsigned short As[2][128 * 64];   // 2 x 16 KB
  __shared__ unsigned short W1s[2][64 * 64];   // 2 x 8 KB
  __shared__ unsigned short W3s[2][64 * 64];   // 2 x 8 KB   (total 64 KB)

  const int tid  = threadIdx.x;
  const int lane = tid & 63;
  const int wv   = tid >> 6;            // 0..7
  const int wm2  = (wv >> 1) * 32;      // wave m-offset (0/32/64/96)
  const int wn2  = (wv & 1) * 32;       // wave n-offset (0/32)
  const int q    = lane >> 4;
  const int l15  = lane & 15;
  const int rsw  = (l15 & 7) << 4;      // read-side swizzle (row&7)<<4

  WORK_LOOP(wl) {
    const unsigned int it_w = wl[1 + j];
    const int mt  = it_w >> 24;
    const int nt  = (it_w >> 21) & 7;
    const int e   = (it_w >> 16) & 15;
    const int rlo = (it_w >> 8) & 255;
    const int rhi = it_w & 255;
    const int t0  = mt * 128;
    const int n0  = nt * 64;

    const unsigned short* __restrict__ w1e = w1b + (size_t)e * HIDq * DIMq;
    const unsigned short* __restrict__ w3e = w3b + (size_t)e * HIDq * DIMq;

    f32x4 acc1[2][2], acc3[2][2];
    #pragma unroll
    for (int i = 0; i < 2; ++i)
      #pragma unroll
      for (int jj = 0; jj < 2; ++jj) { acc1[i][jj] = (f32x4)0.f; acc3[i][jj] = (f32x4)0.f; }

    auto stage = [&](int k0, int bi) {
      #pragma unroll
      for (int it = 0; it < 2; ++it) {                     // A: 128x64 bf16
        const int c = it * 512 + tid;
        const int row = c >> 3;
        const int kc = ((c & 7) << 3) ^ ((row & 7) << 3);  // pre-swizzled source col
        GLOAD16(xb + (size_t)(t0 + row) * DIMq + k0 + kc,
                (char*)&As[bi][0] + it * 8192 + wv * 1024);
      }
      {                                                    // W1,W3: 64x64 each
        const int row = tid >> 3;
        const int kc = ((tid & 7) << 3) ^ ((row & 7) << 3);
        GLOAD16(w1e + (size_t)(n0 + row) * DIMq + k0 + kc,
                (char*)&W1s[bi][0] + wv * 1024);
        GLOAD16(w3e + (size_t)(n0 + row) * DIMq + k0 + kc,
                (char*)&W3s[bi][0] + wv * 1024);
      }
    };
    auto compute = [&](int bi) {
      const char* Ab = (const char*)&As[bi][0];
      const char* Ub = (const char*)&W1s[bi][0];
      const char* Vb = (const char*)&W3s[bi][0];
      #pragma unroll
      for (int ks = 0; ks < 2; ++ks) {
        const int kb = (ks * 64 + q * 16) ^ rsw;           // swizzled read col
        bf16x8 a[2], u[2], v[2];
        #pragma unroll
        for (int i = 0; i < 2; ++i)
          a[i] = *(const bf16x8*)(Ab + (wm2 + i * 16 + l15) * 128 + kb);
        #pragma unroll
        for (int jj = 0; jj < 2; ++jj) {
          u[jj] = *(const bf16x8*)(Ub + (wn2 + jj * 16 + l15) * 128 + kb);
          v[jj] = *(const bf16x8*)(Vb + (wn2 + jj * 16 + l15) * 128 + kb);
        }
        #pragma unroll
        for (int i = 0; i < 2; ++i)
          #pragma unroll
          for (int jj = 0; jj < 2; ++jj) {
            acc1[i][jj] = __builtin_amdgcn_mfma_f32_16x16x32_bf16(a[i], u[jj], acc1[i][jj], 0, 0, 0);
            acc3[i][jj] = __builtin_amdgcn_mfma_f32_16x16x32_bf16(a[i], v[jj], acc3[i][jj], 0, 0, 0);
          }
      }
    };

    stage(0, 0);
    __syncthreads();                     // buf0 ready
    int cur = 0;
    #pragma unroll 1
    for (int k0 = 0; k0 < DIMq; k0 += 64) {
      if (k0 + 64 < DIMq) stage(k0 + 64, cur ^ 1);   // issue next tile FIRST
      compute(cur);                                  // MFMA hides load latency
      __syncthreads();                               // next buf ready; cur free
      cur ^= 1;
    }

    // ---- epilogue: SwiGLU with reference-matching bf16 roundings ----
    #pragma unroll
    for (int i = 0; i < 2; ++i)
      #pragma unroll
      for (int jj = 0; jj < 2; ++jj)
        #pragma unroll
        for (int rr = 0; rr < 4; ++rr) {
          const int row = wm2 + i * 16 + q * 4 + rr;
          if (row >= rlo && row < rhi) {
            const float aa = bf2f(f2bf(acc1[i][jj][rr]));
            const float cc = bf2f(f2bf(acc3[i][jj][rr]));
            const float sg = bf2f(f2bf(1.f / (1.f + __expf(-aa))));
            const float tt = bf2f(f2bf(aa * sg));
            hbuf[(size_t)(t0 + row) * HIDq + n0 + wn2 + jj * 16 + l15] =
                (unsigned short)f2bf(tt * cc);
          }
        }
  }
}

// ---------------------------------------------------------------------------
// Kernel 2: out = f32( bf16( h . w2^T ) ).  Item: 128m x 128n, BK=64,
// 8 waves (wave tile 32x64), same pipeline.
// ---------------------------------------------------------------------------
__global__ __launch_bounds__(512) void gemm2_kernel(
    const unsigned short* __restrict__ hb, const unsigned short* __restrict__ w2b,
    const unsigned int* __restrict__ wl, float* __restrict__ out) {
  __shared__ unsigned short Hs[2][128 * 64];   // 2 x 16 KB
  __shared__ unsigned short Bs[2][128 * 64];   // 2 x 16 KB  (total 64 KB)

  const int tid  = threadIdx.x;
  const int lane = tid & 63;
  const int wv   = tid >> 6;
  const int wm2  = (wv >> 1) * 32;      // 0/32/64/96
  const int wn2  = (wv & 1) * 64;       // 0/64
  const int q    = lane >> 4;
  const int l15  = lane & 15;
  const int rsw  = (l15 & 7) << 4;

  WORK_LOOP(wl) {
    const unsigned int it_w = wl[1 + j];
    const int mt  = it_w >> 24;
    const int nt  = (it_w >> 21) & 7;
    const int e   = (it_w >> 16) & 15;
    const int rlo = (it_w >> 8) & 255;
    const int rhi = it_w & 255;
    const int t0  = mt * 128;
    const int n0  = nt * 128;

    const unsigned short* __restrict__ w2e = w2b + (size_t)e * DIMq * HIDq;

    f32x4 acc[2][4];
    #pragma unroll
    for (int i = 0; i < 2; ++i)
      #pragma unroll
      for (int jj = 0; jj < 4; ++jj) acc[i][jj] = (f32x4)0.f;

    auto stage = [&](int k0, int bi) {
      #pragma unroll
      for (int it = 0; it < 2; ++it) {
        const int c = it * 512 + tid;
        const int row = c >> 3;
        const int kc = ((c & 7) << 3) ^ ((row & 7) << 3);
        GLOAD16(hb + (size_t)(t0 + row) * HIDq + k0 + kc,
                (char*)&Hs[bi][0] + it * 8192 + wv * 1024);
        GLOAD16(w2e + (size_t)(n0 + row) * HIDq + k0 + kc,
                (char*)&Bs[bi][0] + it * 8192 + wv * 1024);
      }
    };
    auto compute = [&](int bi) {
      const char* Ab = (const char*)&Hs[bi][0];
      const char* Wb = (const char*)&Bs[bi][0];
      #pragma unroll
      for (int ks = 0; ks < 2; ++ks) {
        const int kb = (ks * 64 + q * 16) ^ rsw;
        bf16x8 a[2], w[4];
        #pragma unroll
        for (int i = 0; i < 2; ++i)
          a[i] = *(const bf16x8*)(Ab + (wm2 + i * 16 + l15) * 128 + kb);
        #pragma unroll
        for (int jj = 0; jj < 4; ++jj)
          w[jj] = *(const bf16x8*)(Wb + (wn2 + jj * 16 + l15) * 128 + kb);
        #pragma unroll
        for (int i = 0; i < 2; ++i)
          #pragma unroll
          for (int jj = 0; jj < 4; ++jj)
            acc[i][jj] = __builtin_amdgcn_mfma_f32_16x16x32_bf16(a[i], w[jj], acc[i][jj], 0, 0, 0);
      }
    };

    stage(0, 0);
    __syncthreads();
    int cur = 0;
    #pragma unroll 1
    for (int k0 = 0; k0 < HIDq; k0 += 64) {
      if (k0 + 64 < HIDq) stage(k0 + 64, cur ^ 1);
      compute(cur);
      __syncthreads();
      cur ^= 1;
    }

    #pragma unroll
    for (int i = 0; i < 2; ++i)
      #pragma unroll
      for (int jj = 0; jj < 4; ++jj)
        #pragma unroll
        for (int rr = 0; rr < 4; ++rr) {
          const int row = wm2 + i * 16 + q * 4 + rr;
          if (row >= rlo && row < rhi) {
            out[(size_t)(t0 + row) * DIMq + n0 + wn2 + jj * 16 + l15] =
                bf2f(f2bf(acc[i][jj][rr]));   // reference rounds y to bf16
          }
        }
  }
}

// ---------------------------------------------------------------------------
extern "C" void kernel_launch(void* const* d_in, const int* in_sizes, int n_in,
                              void* d_out, int out_size, void* d_ws, size_t ws_size,
                              hipStream_t stream) {
  const float* x      = (const float*)d_in[0];
  const int*   counts = (const int*)d_in[1];
  const float* w1     = (const float*)d_in[2];
  const float* w2     = (const float*)d_in[3];
  const float* w3     = (const float*)d_in[4];
  float* out = (float*)d_out;

  // workspace layout (72 MB + 33 KB)
  char* ws = (char*)d_ws;
  unsigned short* xb  = (unsigned short*)(ws + 256);        // 16 MB
  unsigned short* w1b = (unsigned short*)(ws + 256 + (16u << 20));
  unsigned short* w2b = (unsigned short*)(ws + 256 + (32u << 20));
  unsigned short* w3b = (unsigned short*)(ws + 256 + (48u << 20));
  unsigned short* hb  = (unsigned short*)(ws + 256 + (64u << 20));  // 8 MB
  unsigned int*   wl  = (unsigned int*)(ws + 256 + (72u << 20));    // 32 KB+4

  convert4_kernel<<<dim3(2048, 4), 256, 0, stream>>>(
      x, w1, w2, w3, (ull*)xb, (ull*)w1b, (ull*)w2b, (ull*)w3b);
  setup_worklist<<<1, 64, 0, stream>>>(counts, wl);
  gemm1_kernel<<<512, 512, 0, stream>>>(xb, w1b, w3b, wl, hb);
  gemm2_kernel<<<512, 512, 0, stream>>>(hb, w2b, wl, out);
}

// Round 11
// 229.185 us; speedup vs baseline: 1.5325x; 1.0096x over previous
//
#include <hip/hip_runtime.h>
#include <hip/hip_bf16.h>
#include <stdint.h>

// Problem constants (match reference)
#define Bq   2
#define Tq   4096
#define DIMq 1024
#define HIDq 512
#define Eq   16
#define Mq   (Bq * Tq)   // 8192 flattened token rows

typedef __attribute__((ext_vector_type(8))) short bf16x8;   // 8 bf16 = 4 VGPRs
typedef __attribute__((ext_vector_type(4))) float f32x4;
typedef unsigned long long ull;

// --- bf16 helpers (RNE, matches XLA rounding) ---
__device__ __forceinline__ unsigned int f2bf(float f) {
  unsigned int u = __builtin_bit_cast(unsigned int, f);
  return (u + 0x7FFFu + ((u >> 16) & 1u)) >> 16;
}
__device__ __forceinline__ float bf2f(unsigned int s) {
  unsigned int u = s << 16;
  return __builtin_bit_cast(float, u);
}

// async global->LDS, 16B per lane; lds ptr must be WAVE-UNIFORM base (HW adds lane*16)
#define GLOAD16(gp, lp)                                                        \
  __builtin_amdgcn_global_load_lds(                                            \
      (const __attribute__((address_space(1))) unsigned int*)(gp),             \
      (__attribute__((address_space(3))) unsigned int*)(lp), 16, 0, 0)

// ---------------------------------------------------------------------------
// Kernel A: fp32 -> bf16 conversion for x, w1, w2, w3 (each 8,388,608 floats).
// 8 floats/iter: 2x float4 load (32B) -> 1x uint4 store (16B/lane, G13 sweet
// spot). 2048 blocks total, grid-stride (G11).
// ---------------------------------------------------------------------------
__global__ __launch_bounds__(256) void convert4_kernel(
    const float* __restrict__ x,  const float* __restrict__ w1,
    const float* __restrict__ w2, const float* __restrict__ w3,
    uint4* __restrict__ xb, uint4* __restrict__ w1b,
    uint4* __restrict__ w2b, uint4* __restrict__ w3b) {
  const float* s;
  uint4* d;
  switch (blockIdx.y) {
    case 0:  s = x;  d = xb;  break;
    case 1:  s = w1; d = w1b; break;
    case 2:  s = w2; d = w2b; break;
    default: s = w3; d = w3b; break;
  }
  const int N8 = 8388608 / 8;            // 8-float groups per array
  const float4* s4 = (const float4*)s;
  for (int i = blockIdx.x * blockDim.x + threadIdx.x; i < N8;
       i += gridDim.x * blockDim.x) {
    const float4 a = s4[2 * i];
    const float4 b = s4[2 * i + 1];
    uint4 o;
    o.x = f2bf(a.x) | (f2bf(a.y) << 16);
    o.y = f2bf(a.z) | (f2bf(a.w) << 16);
    o.z = f2bf(b.x) | (f2bf(b.y) << 16);
    o.w = f2bf(b.z) | (f2bf(b.w) << 16);
    d[i] = o;
  }
}

// ---------------------------------------------------------------------------
// Kernel 0: build uniform worklist. One item = (mt, nt, e, rlo, rhi):
// one full K-run on one 128-row m-tile x one n-tile for one expert segment.
// Items sorted by mt (locality). Packed u32:
//   [29:24]=mt  [23:21]=nt  [19:16]=e  [15:8]=rlo  [7:0]=rhi
// wl[0] = N items; items at wl[1..].
// ---------------------------------------------------------------------------
__global__ void setup_worklist(const int* __restrict__ counts,
                               unsigned int* __restrict__ wl) {
  __shared__ int ns_arr[64];
  const int t   = threadIdx.x;          // m-tile id 0..63
  const int b   = t >> 5;
  const int tl0 = (t & 31) * 128;
  int se[16], sl[16], sh[16];
  int ns = 0, lo = 0;
  for (int e = 0; e < Eq; ++e) {
    const int hi = lo + counts[b * Eq + e];
    const int s  = lo > tl0 ? lo : tl0;
    const int en = hi < tl0 + 128 ? hi : tl0 + 128;
    if (s < en) { se[ns] = e; sl[ns] = s - tl0; sh[ns] = en - tl0; ++ns; }
    lo = hi;
  }
  ns_arr[t] = ns;
  __syncthreads();
  int off = 0;
  for (int i = 0; i < t; ++i) off += ns_arr[i];
  for (int k = 0; k < ns; ++k)
    for (int nt = 0; nt < 8; ++nt)
      wl[1 + (off + k) * 8 + nt] =
          ((unsigned int)t << 24) | ((unsigned int)nt << 21) |
          ((unsigned int)se[k] << 16) | ((unsigned int)sl[k] << 8) |
          (unsigned int)sh[k];
  if (t == 63) wl[0] = (unsigned int)((off + ns) * 8);
}

// XCD-sliced grid-stride: XCD c (= bid&7, per m09 bid%8->XCD) owns the
// contiguous worklist slice [c*q, (c+1)*q); block s=bid>>3 strides by 64
// inside the slice. mt-sorted list => slice shares x/h panels in one L2.
#define WORK_LOOP(wlptr)                                                       \
  const int Nw = (int)wlptr[0];                                                \
  const int qw = (Nw + 7) >> 3;                                                \
  const int cx = blockIdx.x & 7, sx = blockIdx.x >> 3;                         \
  const int jend = min((cx + 1) * qw, Nw);                                     \
  for (int j = cx * qw + sx; j < jend; j += 64)

// ---------------------------------------------------------------------------
// Kernel 1: h = bf16( silu(x.w1^T) * (x.w3^T) )
// Item: 128m x 64n, BK=64, 8 waves (wave tile 32x32), double-buffered LDS,
// stage-before-compute, XOR-swizzle via pre-swizzled global source.
// ---------------------------------------------------------------------------
__global__ __launch_bounds__(512) void gemm1_kernel(
    const unsigned short* __restrict__ xb, const unsigned short* __restrict__ w1b,
    const unsigned short* __restrict__ w3b, const unsigned int* __restrict__ wl,
    unsigned short* __restrict__ hbuf) {
  __shared__ unsigned short As[2][128 * 64];   // 2 x 16 KB
  __shared__ unsigned short W1s[2][64 * 64];   // 2 x 8 KB
  __shared__ unsigned short W3s[2][64 * 64];   // 2 x 8 KB   (total 64 KB)

  const int tid  = threadIdx.x;
  const int lane = tid & 63;
  const int wv   = tid >> 6;            // 0..7
  const int wm2  = (wv >> 1) * 32;      // wave m-offset (0/32/64/96)
  const int wn2  = (wv & 1) * 32;       // wave n-offset (0/32)
  const int q    = lane >> 4;
  const int l15  = lane & 15;
  const int rsw  = (l15 & 7) << 4;      // read-side swizzle (row&7)<<4

  WORK_LOOP(wl) {
    const unsigned int it_w = wl[1 + j];
    const int mt  = it_w >> 24;
    const int nt  = (it_w >> 21) & 7;
    const int e   = (it_w >> 16) & 15;
    const int rlo = (it_w >> 8) & 255;
    const int rhi = it_w & 255;
    const int t0  = mt * 128;
    const int n0  = nt * 64;

    const unsigned short* __restrict__ w1e = w1b + (size_t)e * HIDq * DIMq;
    const unsigned short* __restrict__ w3e = w3b + (size_t)e * HIDq * DIMq;

    f32x4 acc1[2][2], acc3[2][2];
    #pragma unroll
    for (int i = 0; i < 2; ++i)
      #pragma unroll
      for (int jj = 0; jj < 2; ++jj) { acc1[i][jj] = (f32x4)0.f; acc3[i][jj] = (f32x4)0.f; }

    auto stage = [&](int k0, int bi) {
      #pragma unroll
      for (int it = 0; it < 2; ++it) {                     // A: 128x64 bf16
        const int c = it * 512 + tid;
        const int row = c >> 3;
        const int kc = ((c & 7) << 3) ^ ((row & 7) << 3);  // pre-swizzled source col
        GLOAD16(xb + (size_t)(t0 + row) * DIMq + k0 + kc,
                (char*)&As[bi][0] + it * 8192 + wv * 1024);
      }
      {                                                    // W1,W3: 64x64 each
        const int row = tid >> 3;
        const int kc = ((tid & 7) << 3) ^ ((row & 7) << 3);
        GLOAD16(w1e + (size_t)(n0 + row) * DIMq + k0 + kc,
                (char*)&W1s[bi][0] + wv * 1024);
        GLOAD16(w3e + (size_t)(n0 + row) * DIMq + k0 + kc,
                (char*)&W3s[bi][0] + wv * 1024);
      }
    };
    auto compute = [&](int bi) {
      const char* Ab = (const char*)&As[bi][0];
      const char* Ub = (const char*)&W1s[bi][0];
      const char* Vb = (const char*)&W3s[bi][0];
      #pragma unroll
      for (int ks = 0; ks < 2; ++ks) {
        const int kb = (ks * 64 + q * 16) ^ rsw;           // swizzled read col
        bf16x8 a[2], u[2], v[2];
        #pragma unroll
        for (int i = 0; i < 2; ++i)
          a[i] = *(const bf16x8*)(Ab + (wm2 + i * 16 + l15) * 128 + kb);
        #pragma unroll
        for (int jj = 0; jj < 2; ++jj) {
          u[jj] = *(const bf16x8*)(Ub + (wn2 + jj * 16 + l15) * 128 + kb);
          v[jj] = *(const bf16x8*)(Vb + (wn2 + jj * 16 + l15) * 128 + kb);
        }
        #pragma unroll
        for (int i = 0; i < 2; ++i)
          #pragma unroll
          for (int jj = 0; jj < 2; ++jj) {
            acc1[i][jj] = __builtin_amdgcn_mfma_f32_16x16x32_bf16(a[i], u[jj], acc1[i][jj], 0, 0, 0);
            acc3[i][jj] = __builtin_amdgcn_mfma_f32_16x16x32_bf16(a[i], v[jj], acc3[i][jj], 0, 0, 0);
          }
      }
    };

    stage(0, 0);
    __syncthreads();                     // buf0 ready
    int cur = 0;
    #pragma unroll 1
    for (int k0 = 0; k0 < DIMq; k0 += 64) {
      if (k0 + 64 < DIMq) stage(k0 + 64, cur ^ 1);   // issue next tile FIRST
      compute(cur);                                  // MFMA hides load latency
      __syncthreads();                               // next buf ready; cur free
      cur ^= 1;
    }

    // ---- epilogue: SwiGLU with reference-matching bf16 roundings ----
    #pragma unroll
    for (int i = 0; i < 2; ++i)
      #pragma unroll
      for (int jj = 0; jj < 2; ++jj)
        #pragma unroll
        for (int rr = 0; rr < 4; ++rr) {
          const int row = wm2 + i * 16 + q * 4 + rr;
          if (row >= rlo && row < rhi) {
            const float aa = bf2f(f2bf(acc1[i][jj][rr]));
            const float cc = bf2f(f2bf(acc3[i][jj][rr]));
            const float sg = bf2f(f2bf(1.f / (1.f + __expf(-aa))));
            const float tt = bf2f(f2bf(aa * sg));
            hbuf[(size_t)(t0 + row) * HIDq + n0 + wn2 + jj * 16 + l15] =
                (unsigned short)f2bf(tt * cc);
          }
        }
  }
}

// ---------------------------------------------------------------------------
// Kernel 2: out = f32( bf16( h . w2^T ) ).  Item: 128m x 128n, BK=64,
// 8 waves (wave tile 32x64), same pipeline.
// ---------------------------------------------------------------------------
__global__ __launch_bounds__(512) void gemm2_kernel(
    const unsigned short* __restrict__ hb, const unsigned short* __restrict__ w2b,
    const unsigned int* __restrict__ wl, float* __restrict__ out) {
  __shared__ unsigned short Hs[2][128 * 64];   // 2 x 16 KB
  __shared__ unsigned short Bs[2][128 * 64];   // 2 x 16 KB  (total 64 KB)

  const int tid  = threadIdx.x;
  const int lane = tid & 63;
  const int wv   = tid >> 6;
  const int wm2  = (wv >> 1) * 32;      // 0/32/64/96
  const int wn2  = (wv & 1) * 64;       // 0/64
  const int q    = lane >> 4;
  const int l15  = lane & 15;
  const int rsw  = (l15 & 7) << 4;

  WORK_LOOP(wl) {
    const unsigned int it_w = wl[1 + j];
    const int mt  = it_w >> 24;
    const int nt  = (it_w >> 21) & 7;
    const int e   = (it_w >> 16) & 15;
    const int rlo = (it_w >> 8) & 255;
    const int rhi = it_w & 255;
    const int t0  = mt * 128;
    const int n0  = nt * 128;

    const unsigned short* __restrict__ w2e = w2b + (size_t)e * DIMq * HIDq;

    f32x4 acc[2][4];
    #pragma unroll
    for (int i = 0; i < 2; ++i)
      #pragma unroll
      for (int jj = 0; jj < 4; ++jj) acc[i][jj] = (f32x4)0.f;

    auto stage = [&](int k0, int bi) {
      #pragma unroll
      for (int it = 0; it < 2; ++it) {
        const int c = it * 512 + tid;
        const int row = c >> 3;
        const int kc = ((c & 7) << 3) ^ ((row & 7) << 3);
        GLOAD16(hb + (size_t)(t0 + row) * HIDq + k0 + kc,
                (char*)&Hs[bi][0] + it * 8192 + wv * 1024);
        GLOAD16(w2e + (size_t)(n0 + row) * HIDq + k0 + kc,
                (char*)&Bs[bi][0] + it * 8192 + wv * 1024);
      }
    };
    auto compute = [&](int bi) {
      const char* Ab = (const char*)&Hs[bi][0];
      const char* Wb = (const char*)&Bs[bi][0];
      #pragma unroll
      for (int ks = 0; ks < 2; ++ks) {
        const int kb = (ks * 64 + q * 16) ^ rsw;
        bf16x8 a[2], w[4];
        #pragma unroll
        for (int i = 0; i < 2; ++i)
          a[i] = *(const bf16x8*)(Ab + (wm2 + i * 16 + l15) * 128 + kb);
        #pragma unroll
        for (int jj = 0; jj < 4; ++jj)
          w[jj] = *(const bf16x8*)(Wb + (wn2 + jj * 16 + l15) * 128 + kb);
        #pragma unroll
        for (int i = 0; i < 2; ++i)
          #pragma unroll
          for (int jj = 0; jj < 4; ++jj)
            acc[i][jj] = __builtin_amdgcn_mfma_f32_16x16x32_bf16(a[i], w[jj], acc[i][jj], 0, 0, 0);
      }
    };

    stage(0, 0);
    __syncthreads();
    int cur = 0;
    #pragma unroll 1
    for (int k0 = 0; k0 < HIDq; k0 += 64) {
      if (k0 + 64 < HIDq) stage(k0 + 64, cur ^ 1);
      compute(cur);
      __syncthreads();
      cur ^= 1;
    }

    #pragma unroll
    for (int i = 0; i < 2; ++i)
      #pragma unroll
      for (int jj = 0; jj < 4; ++jj)
        #pragma unroll
        for (int rr = 0; rr < 4; ++rr) {
          const int row = wm2 + i * 16 + q * 4 + rr;
          if (row >= rlo && row < rhi) {
            out[(size_t)(t0 + row) * DIMq + n0 + wn2 + jj * 16 + l15] =
                bf2f(f2bf(acc[i][jj][rr]));   // reference rounds y to bf16
          }
        }
  }
}

// ---------------------------------------------------------------------------
extern "C" void kernel_launch(void* const* d_in, const int* in_sizes, int n_in,
                              void* d_out, int out_size, void* d_ws, size_t ws_size,
                              hipStream_t stream) {
  const float* x      = (const float*)d_in[0];
  const int*   counts = (const int*)d_in[1];
  const float* w1     = (const float*)d_in[2];
  const float* w2     = (const float*)d_in[3];
  const float* w3     = (const float*)d_in[4];
  float* out = (float*)d_out;

  // workspace layout (72 MB + 33 KB)
  char* ws = (char*)d_ws;
  unsigned short* xb  = (unsigned short*)(ws + 256);        // 16 MB
  unsigned short* w1b = (unsigned short*)(ws + 256 + (16u << 20));
  unsigned short* w2b = (unsigned short*)(ws + 256 + (32u << 20));
  unsigned short* w3b = (unsigned short*)(ws + 256 + (48u << 20));
  unsigned short* hb  = (unsigned short*)(ws + 256 + (64u << 20));  // 8 MB
  unsigned int*   wl  = (unsigned int*)(ws + 256 + (72u << 20));    // 32 KB+4

  setup_worklist<<<1, 64, 0, stream>>>(counts, wl);
  convert4_kernel<<<dim3(512, 4), 256, 0, stream>>>(
      x, w1, w2, w3, (uint4*)xb, (uint4*)w1b, (uint4*)w2b, (uint4*)w3b);
  gemm1_kernel<<<512, 512, 0, stream>>>(xb, w1b, w3b, wl, hb);
  gemm2_kernel<<<512, 512, 0, stream>>>(hb, w2b, wl, out);
}

// Round 12
// 228.536 us; speedup vs baseline: 1.5368x; 1.0028x over previous
//
#include <hip/hip_runtime.h>
#include <hip/hip_bf16.h>
#include <stdint.h>

// Problem constants (match reference)
#define Bq   2
#define Tq   4096
#define DIMq 1024
#define HIDq 512
#define Eq   16
#define Mq   (Bq * Tq)   // 8192 flattened token rows

typedef __attribute__((ext_vector_type(8))) short bf16x8;   // 8 bf16 = 4 VGPRs
typedef __attribute__((ext_vector_type(4))) float f32x4;
typedef unsigned long long ull;

// --- bf16 helpers (RNE, matches XLA rounding) ---
__device__ __forceinline__ unsigned int f2bf(float f) {
  unsigned int u = __builtin_bit_cast(unsigned int, f);
  return (u + 0x7FFFu + ((u >> 16) & 1u)) >> 16;
}
__device__ __forceinline__ float bf2f(unsigned int s) {
  unsigned int u = s << 16;
  return __builtin_bit_cast(float, u);
}

// async global->LDS, 16B per lane; lds ptr must be WAVE-UNIFORM base (HW adds lane*16)
#define GLOAD16(gp, lp)                                                        \
  __builtin_amdgcn_global_load_lds(                                            \
      (const __attribute__((address_space(1))) unsigned int*)(gp),             \
      (__attribute__((address_space(3))) unsigned int*)(lp), 16, 0, 0)

// ---------------------------------------------------------------------------
// Kernel A: fp32 -> bf16 conversion for x, w1, w2, w3 (each 8,388,608 floats).
// ILP fix: exact trip count 4, fully unrolled -> 8 float4 loads in flight
// per thread before first store (round-11 had VGPR=12, zero cross-iter ILP).
// ---------------------------------------------------------------------------
__global__ __launch_bounds__(256) void convert4_kernel(
    const float* __restrict__ x,  const float* __restrict__ w1,
    const float* __restrict__ w2, const float* __restrict__ w3,
    uint4* __restrict__ xb, uint4* __restrict__ w1b,
    uint4* __restrict__ w2b, uint4* __restrict__ w3b) {
  const float* s;
  uint4* d;
  switch (blockIdx.y) {
    case 0:  s = x;  d = xb;  break;
    case 1:  s = w1; d = w1b; break;
    case 2:  s = w2; d = w2b; break;
    default: s = w3; d = w3b; break;
  }
  const int base = blockIdx.x * 256 + threadIdx.x;   // 0..262143
  const float4* s4 = (const float4*)s;
  float4 a[4], b[4];
  #pragma unroll
  for (int it = 0; it < 4; ++it) {                   // issue all loads first
    const int i = base + it * 262144;
    a[it] = s4[2 * i];
    b[it] = s4[2 * i + 1];
  }
  #pragma unroll
  for (int it = 0; it < 4; ++it) {
    const int i = base + it * 262144;
    uint4 o;
    o.x = f2bf(a[it].x) | (f2bf(a[it].y) << 16);
    o.y = f2bf(a[it].z) | (f2bf(a[it].w) << 16);
    o.z = f2bf(b[it].x) | (f2bf(b[it].y) << 16);
    o.w = f2bf(b[it].z) | (f2bf(b[it].w) << 16);
    d[i] = o;
  }
}

// ---------------------------------------------------------------------------
// Kernel 0: build uniform worklist. One item = (mt, nt, e, rlo, rhi):
// one full K-run on one 128-row m-tile x one n-tile for one expert segment.
// Items sorted by mt (locality). Packed u32:
//   [29:24]=mt  [23:21]=nt  [19:16]=e  [15:8]=rlo  [7:0]=rhi
// wl[0] = N items; items at wl[1..].
// ---------------------------------------------------------------------------
__global__ void setup_worklist(const int* __restrict__ counts,
                               unsigned int* __restrict__ wl) {
  __shared__ int ns_arr[64];
  const int t   = threadIdx.x;          // m-tile id 0..63
  const int b   = t >> 5;
  const int tl0 = (t & 31) * 128;
  int se[16], sl[16], sh[16];
  int ns = 0, lo = 0;
  for (int e = 0; e < Eq; ++e) {
    const int hi = lo + counts[b * Eq + e];
    const int s  = lo > tl0 ? lo : tl0;
    const int en = hi < tl0 + 128 ? hi : tl0 + 128;
    if (s < en) { se[ns] = e; sl[ns] = s - tl0; sh[ns] = en - tl0; ++ns; }
    lo = hi;
  }
  ns_arr[t] = ns;
  __syncthreads();
  int off = 0;
  for (int i = 0; i < t; ++i) off += ns_arr[i];
  for (int k = 0; k < ns; ++k)
    for (int nt = 0; nt < 8; ++nt)
      wl[1 + (off + k) * 8 + nt] =
          ((unsigned int)t << 24) | ((unsigned int)nt << 21) |
          ((unsigned int)se[k] << 16) | ((unsigned int)sl[k] << 8) |
          (unsigned int)sh[k];
  if (t == 63) wl[0] = (unsigned int)((off + ns) * 8);
}

// XCD-sliced grid-stride: XCD c (= bid&7, per m09 bid%8->XCD) owns the
// contiguous worklist slice [c*q, (c+1)*q); block s=bid>>3 strides by 64
// inside the slice. mt-sorted list => slice shares x/h panels in one L2.
#define WORK_LOOP(wlptr)                                                       \
  const int Nw = (int)wlptr[0];                                                \
  const int qw = (Nw + 7) >> 3;                                                \
  const int cx = blockIdx.x & 7, sx = blockIdx.x >> 3;                         \
  const int jend = min((cx + 1) * qw, Nw);                                     \
  for (int j = cx * qw + sx; j < jend; j += 64)

// ---------------------------------------------------------------------------
// Kernel 1: h = bf16( silu(x.w1^T) * (x.w3^T) )
// Item: 128m x 64n, BK=64, 8 waves (wave tile 32x32), double-buffered LDS,
// stage-before-compute, XOR-swizzle via pre-swizzled global source.
// ---------------------------------------------------------------------------
__global__ __launch_bounds__(512) void gemm1_kernel(
    const unsigned short* __restrict__ xb, const unsigned short* __restrict__ w1b,
    const unsigned short* __restrict__ w3b, const unsigned int* __restrict__ wl,
    unsigned short* __restrict__ hbuf) {
  __shared__ unsigned short As[2][128 * 64];   // 2 x 16 KB
  __shared__ unsigned short W1s[2][64 * 64];   // 2 x 8 KB
  __shared__ unsigned short W3s[2][64 * 64];   // 2 x 8 KB   (total 64 KB)

  const int tid  = threadIdx.x;
  const int lane = tid & 63;
  const int wv   = tid >> 6;            // 0..7
  const int wm2  = (wv >> 1) * 32;      // wave m-offset (0/32/64/96)
  const int wn2  = (wv & 1) * 32;       // wave n-offset (0/32)
  const int q    = lane >> 4;
  const int l15  = lane & 15;
  const int rsw  = (l15 & 7) << 4;      // read-side swizzle (row&7)<<4

  WORK_LOOP(wl) {
    const unsigned int it_w = wl[1 + j];
    const int mt  = it_w >> 24;
    const int nt  = (it_w >> 21) & 7;
    const int e   = (it_w >> 16) & 15;
    const int rlo = (it_w >> 8) & 255;
    const int rhi = it_w & 255;
    const int t0  = mt * 128;
    const int n0  = nt * 64;

    const unsigned short* __restrict__ w1e = w1b + (size_t)e * HIDq * DIMq;
    const unsigned short* __restrict__ w3e = w3b + (size_t)e * HIDq * DIMq;

    f32x4 acc1[2][2], acc3[2][2];
    #pragma unroll
    for (int i = 0; i < 2; ++i)
      #pragma unroll
      for (int jj = 0; jj < 2; ++jj) { acc1[i][jj] = (f32x4)0.f; acc3[i][jj] = (f32x4)0.f; }

    auto stage = [&](int k0, int bi) {
      #pragma unroll
      for (int it = 0; it < 2; ++it) {                     // A: 128x64 bf16
        const int c = it * 512 + tid;
        const int row = c >> 3;
        const int kc = ((c & 7) << 3) ^ ((row & 7) << 3);  // pre-swizzled source col
        GLOAD16(xb + (size_t)(t0 + row) * DIMq + k0 + kc,
                (char*)&As[bi][0] + it * 8192 + wv * 1024);
      }
      {                                                    // W1,W3: 64x64 each
        const int row = tid >> 3;
        const int kc = ((tid & 7) << 3) ^ ((row & 7) << 3);
        GLOAD16(w1e + (size_t)(n0 + row) * DIMq + k0 + kc,
                (char*)&W1s[bi][0] + wv * 1024);
        GLOAD16(w3e + (size_t)(n0 + row) * DIMq + k0 + kc,
                (char*)&W3s[bi][0] + wv * 1024);
      }
    };
    auto compute = [&](int bi) {
      const char* Ab = (const char*)&As[bi][0];
      const char* Ub = (const char*)&W1s[bi][0];
      const char* Vb = (const char*)&W3s[bi][0];
      #pragma unroll
      for (int ks = 0; ks < 2; ++ks) {
        const int kb = (ks * 64 + q * 16) ^ rsw;           // swizzled read col
        bf16x8 a[2], u[2], v[2];
        #pragma unroll
        for (int i = 0; i < 2; ++i)
          a[i] = *(const bf16x8*)(Ab + (wm2 + i * 16 + l15) * 128 + kb);
        #pragma unroll
        for (int jj = 0; jj < 2; ++jj) {
          u[jj] = *(const bf16x8*)(Ub + (wn2 + jj * 16 + l15) * 128 + kb);
          v[jj] = *(const bf16x8*)(Vb + (wn2 + jj * 16 + l15) * 128 + kb);
        }
        #pragma unroll
        for (int i = 0; i < 2; ++i)
          #pragma unroll
          for (int jj = 0; jj < 2; ++jj) {
            acc1[i][jj] = __builtin_amdgcn_mfma_f32_16x16x32_bf16(a[i], u[jj], acc1[i][jj], 0, 0, 0);
            acc3[i][jj] = __builtin_amdgcn_mfma_f32_16x16x32_bf16(a[i], v[jj], acc3[i][jj], 0, 0, 0);
          }
      }
    };

    stage(0, 0);
    __syncthreads();                     // buf0 ready
    int cur = 0;
    #pragma unroll 1
    for (int k0 = 0; k0 < DIMq; k0 += 64) {
      if (k0 + 64 < DIMq) stage(k0 + 64, cur ^ 1);   // issue next tile FIRST
      compute(cur);                                  // MFMA hides load latency
      __syncthreads();                               // next buf ready; cur free
      cur ^= 1;
    }

    // ---- epilogue: SwiGLU with reference-matching bf16 roundings ----
    #pragma unroll
    for (int i = 0; i < 2; ++i)
      #pragma unroll
      for (int jj = 0; jj < 2; ++jj)
        #pragma unroll
        for (int rr = 0; rr < 4; ++rr) {
          const int row = wm2 + i * 16 + q * 4 + rr;
          if (row >= rlo && row < rhi) {
            const float aa = bf2f(f2bf(acc1[i][jj][rr]));
            const float cc = bf2f(f2bf(acc3[i][jj][rr]));
            const float sg = bf2f(f2bf(1.f / (1.f + __expf(-aa))));
            const float tt = bf2f(f2bf(aa * sg));
            hbuf[(size_t)(t0 + row) * HIDq + n0 + wn2 + jj * 16 + l15] =
                (unsigned short)f2bf(tt * cc);
          }
        }
  }
}

// ---------------------------------------------------------------------------
// Kernel 2: out = f32( bf16( h . w2^T ) ).  Item: 128m x 128n, BK=64,
// 8 waves (wave tile 32x64), same pipeline.
// ---------------------------------------------------------------------------
__global__ __launch_bounds__(512) void gemm2_kernel(
    const unsigned short* __restrict__ hb, const unsigned short* __restrict__ w2b,
    const unsigned int* __restrict__ wl, float* __restrict__ out) {
  __shared__ unsigned short Hs[2][128 * 64];   // 2 x 16 KB
  __shared__ unsigned short Bs[2][128 * 64];   // 2 x 16 KB  (total 64 KB)

  const int tid  = threadIdx.x;
  const int lane = tid & 63;
  const int wv   = tid >> 6;
  const int wm2  = (wv >> 1) * 32;      // 0/32/64/96
  const int wn2  = (wv & 1) * 64;       // 0/64
  const int q    = lane >> 4;
  const int l15  = lane & 15;
  const int rsw  = (l15 & 7) << 4;

  WORK_LOOP(wl) {
    const unsigned int it_w = wl[1 + j];
    const int mt  = it_w >> 24;
    const int nt  = (it_w >> 21) & 7;
    const int e   = (it_w >> 16) & 15;
    const int rlo = (it_w >> 8) & 255;
    const int rhi = it_w & 255;
    const int t0  = mt * 128;
    const int n0  = nt * 128;

    const unsigned short* __restrict__ w2e = w2b + (size_t)e * DIMq * HIDq;

    f32x4 acc[2][4];
    #pragma unroll
    for (int i = 0; i < 2; ++i)
      #pragma unroll
      for (int jj = 0; jj < 4; ++jj) acc[i][jj] = (f32x4)0.f;

    auto stage = [&](int k0, int bi) {
      #pragma unroll
      for (int it = 0; it < 2; ++it) {
        const int c = it * 512 + tid;
        const int row = c >> 3;
        const int kc = ((c & 7) << 3) ^ ((row & 7) << 3);
        GLOAD16(hb + (size_t)(t0 + row) * HIDq + k0 + kc,
                (char*)&Hs[bi][0] + it * 8192 + wv * 1024);
        GLOAD16(w2e + (size_t)(n0 + row) * HIDq + k0 + kc,
                (char*)&Bs[bi][0] + it * 8192 + wv * 1024);
      }
    };
    auto compute = [&](int bi) {
      const char* Ab = (const char*)&Hs[bi][0];
      const char* Wb = (const char*)&Bs[bi][0];
      #pragma unroll
      for (int ks = 0; ks < 2; ++ks) {
        const int kb = (ks * 64 + q * 16) ^ rsw;
        bf16x8 a[2], w[4];
        #pragma unroll
        for (int i = 0; i < 2; ++i)
          a[i] = *(const bf16x8*)(Ab + (wm2 + i * 16 + l15) * 128 + kb);
        #pragma unroll
        for (int jj = 0; jj < 4; ++jj)
          w[jj] = *(const bf16x8*)(Wb + (wn2 + jj * 16 + l15) * 128 + kb);
        #pragma unroll
        for (int i = 0; i < 2; ++i)
          #pragma unroll
          for (int jj = 0; jj < 4; ++jj)
            acc[i][jj] = __builtin_amdgcn_mfma_f32_16x16x32_bf16(a[i], w[jj], acc[i][jj], 0, 0, 0);
      }
    };

    stage(0, 0);
    __syncthreads();
    int cur = 0;
    #pragma unroll 1
    for (int k0 = 0; k0 < HIDq; k0 += 64) {
      if (k0 + 64 < HIDq) stage(k0 + 64, cur ^ 1);
      compute(cur);
      __syncthreads();
      cur ^= 1;
    }

    #pragma unroll
    for (int i = 0; i < 2; ++i)
      #pragma unroll
      for (int jj = 0; jj < 4; ++jj)
        #pragma unroll
        for (int rr = 0; rr < 4; ++rr) {
          const int row = wm2 + i * 16 + q * 4 + rr;
          if (row >= rlo && row < rhi) {
            out[(size_t)(t0 + row) * DIMq + n0 + wn2 + jj * 16 + l15] =
                bf2f(f2bf(acc[i][jj][rr]));   // reference rounds y to bf16
          }
        }
  }
}

// ---------------------------------------------------------------------------
extern "C" void kernel_launch(void* const* d_in, const int* in_sizes, int n_in,
                              void* d_out, int out_size, void* d_ws, size_t ws_size,
                              hipStream_t stream) {
  const float* x      = (const float*)d_in[0];
  const int*   counts = (const int*)d_in[1];
  const float* w1     = (const float*)d_in[2];
  const float* w2     = (const float*)d_in[3];
  const float* w3     = (const float*)d_in[4];
  float* out = (float*)d_out;

  // workspace layout (72 MB + 33 KB)
  char* ws = (char*)d_ws;
  unsigned short* xb  = (unsigned short*)(ws + 256);        // 16 MB
  unsigned short* w1b = (unsigned short*)(ws + 256 + (16u << 20));
  unsigned short* w2b = (unsigned short*)(ws + 256 + (32u << 20));
  unsigned short* w3b = (unsigned short*)(ws + 256 + (48u << 20));
  unsigned short* hb  = (unsigned short*)(ws + 256 + (64u << 20));  // 8 MB
  unsigned int*   wl  = (unsigned int*)(ws + 256 + (72u << 20));    // 32 KB+4

  setup_worklist<<<1, 64, 0, stream>>>(counts, wl);
  convert4_kernel<<<dim3(1024, 4), 256, 0, stream>>>(
      x, w1, w2, w3, (uint4*)xb, (uint4*)w1b, (uint4*)w2b, (uint4*)w3b);
  gemm1_kernel<<<512, 512, 0, stream>>>(xb, w1b, w3b, wl, hb);
  gemm2_kernel<<<512, 512, 0, stream>>>(hb, w2b, wl, out);
}